// Round 1
// baseline (4819.754 us; speedup 1.0000x reference)
//
#include <hip/hip_runtime.h>
#include <hip/hip_bf16.h>
#include <math.h>

#define B_ 2
#define T_ 2048
#define D_ 512
#define H_ 8
#define NL_ 4
#define V_ 32000
#define HD_ 64
#define BT_ (B_*T_)
#define EPS_ 1e-5f
#define SCALE_ 0.04419417382415922f  /* 1/sqrt(512) — source scales by D, not HD */

// ---------------------------------------------------------------- embed
__global__ __launch_bounds__(256) void embed_kernel(
    const int* __restrict__ ids, const float* __restrict__ tok,
    const float* __restrict__ pos, float* __restrict__ x)
{
  int i = blockIdx.x * 256 + threadIdx.x;   // float4 index over BT_*D_/4
  int d4 = i & (D_/4 - 1);
  int bt = i >> 7;                          // / (D_/4)
  int t  = bt & (T_ - 1);
  const float4 a = reinterpret_cast<const float4*>(tok + (size_t)ids[bt] * D_)[d4];
  const float4 p = reinterpret_cast<const float4*>(pos + (size_t)t * D_)[d4];
  float4 r; r.x = a.x + p.x; r.y = a.y + p.y; r.z = a.z + p.z; r.w = a.w + p.w;
  reinterpret_cast<float4*>(x)[i] = r;
}

// ---------------------------------------------------------------- layernorm (wave per row, D=512)
__global__ __launch_bounds__(256) void ln_kernel(
    const float* __restrict__ x, const float* __restrict__ g,
    const float* __restrict__ b, float* __restrict__ out)
{
  int row  = blockIdx.x * 4 + (threadIdx.x >> 6);
  int lane = threadIdx.x & 63;
  const float4* xr = reinterpret_cast<const float4*>(x + (size_t)row * D_);
  float4 v0 = xr[lane], v1 = xr[lane + 64];
  float s = v0.x + v0.y + v0.z + v0.w + v1.x + v1.y + v1.z + v1.w;
  float q = v0.x*v0.x + v0.y*v0.y + v0.z*v0.z + v0.w*v0.w
          + v1.x*v1.x + v1.y*v1.y + v1.z*v1.z + v1.w*v1.w;
  #pragma unroll
  for (int off = 1; off < 64; off <<= 1) {
    s += __shfl_xor(s, off);
    q += __shfl_xor(q, off);
  }
  float mean = s * (1.0f / D_);
  float var  = q * (1.0f / D_) - mean * mean;
  float rs   = rsqrtf(var + EPS_);
  const float4* g4 = reinterpret_cast<const float4*>(g);
  const float4* b4 = reinterpret_cast<const float4*>(b);
  float4 gv0 = g4[lane], gv1 = g4[lane + 64];
  float4 bv0 = b4[lane], bv1 = b4[lane + 64];
  float4 o0, o1;
  o0.x = (v0.x - mean) * rs * gv0.x + bv0.x;
  o0.y = (v0.y - mean) * rs * gv0.y + bv0.y;
  o0.z = (v0.z - mean) * rs * gv0.z + bv0.z;
  o0.w = (v0.w - mean) * rs * gv0.w + bv0.w;
  o1.x = (v1.x - mean) * rs * gv1.x + bv1.x;
  o1.y = (v1.y - mean) * rs * gv1.y + bv1.y;
  o1.z = (v1.z - mean) * rs * gv1.z + bv1.z;
  o1.w = (v1.w - mean) * rs * gv1.w + bv1.w;
  float4* o4 = reinterpret_cast<float4*>(out + (size_t)row * D_);
  o4[lane] = o0; o4[lane + 64] = o1;
}

// ---------------------------------------------------------------- generic fp32 GEMM
// C[M x N] = A[M x K] @ B[K x N] (+bias)(+resid)(relu?) ; all dims tile-aligned (M%64==0, N%64==0, K%16==0)
__global__ __launch_bounds__(256) void gemm_kernel(
    const float* __restrict__ A, int lda,
    const float* __restrict__ Bm, int ldb,
    const float* __restrict__ bias,
    const float* __restrict__ resid, int ldr,
    float* __restrict__ C, int ldc,
    int K, int relu)
{
  __shared__ float As[16][68];   // As[k][m] (transposed), pad 68 keeps float4 aligned
  __shared__ float Bs[16][68];   // Bs[k][n]
  const int tid = threadIdx.x;
  const int bm = blockIdx.x * 64, bn = blockIdx.y * 64;
  const int ty = tid >> 4, tx = tid & 15;
  const int ar = tid >> 2, ac4 = (tid & 3) * 4;   // A tile loader coords
  const int br = tid >> 4, bc4 = (tid & 15) * 4;  // B tile loader coords
  float acc[4][4] = {{0.f,0.f,0.f,0.f},{0.f,0.f,0.f,0.f},{0.f,0.f,0.f,0.f},{0.f,0.f,0.f,0.f}};

  for (int k0 = 0; k0 < K; k0 += 16) {
    float4 av = *reinterpret_cast<const float4*>(A + (size_t)(bm + ar) * lda + k0 + ac4);
    float4 bv = *reinterpret_cast<const float4*>(Bm + (size_t)(k0 + br) * ldb + bn + bc4);
    __syncthreads();
    As[ac4+0][ar] = av.x; As[ac4+1][ar] = av.y; As[ac4+2][ar] = av.z; As[ac4+3][ar] = av.w;
    *reinterpret_cast<float4*>(&Bs[br][bc4]) = bv;
    __syncthreads();
    #pragma unroll
    for (int kk = 0; kk < 16; kk++) {
      const float4 a4 = *reinterpret_cast<const float4*>(&As[kk][ty*4]);
      const float4 b4 = *reinterpret_cast<const float4*>(&Bs[kk][tx*4]);
      acc[0][0] += a4.x*b4.x; acc[0][1] += a4.x*b4.y; acc[0][2] += a4.x*b4.z; acc[0][3] += a4.x*b4.w;
      acc[1][0] += a4.y*b4.x; acc[1][1] += a4.y*b4.y; acc[1][2] += a4.y*b4.z; acc[1][3] += a4.y*b4.w;
      acc[2][0] += a4.z*b4.x; acc[2][1] += a4.z*b4.y; acc[2][2] += a4.z*b4.z; acc[2][3] += a4.z*b4.w;
      acc[3][0] += a4.w*b4.x; acc[3][1] += a4.w*b4.y; acc[3][2] += a4.w*b4.z; acc[3][3] += a4.w*b4.w;
    }
  }
  #pragma unroll
  for (int i = 0; i < 4; i++) {
    int r = bm + ty*4 + i;
    #pragma unroll
    for (int j = 0; j < 4; j++) {
      int c = bn + tx*4 + j;
      float vv = acc[i][j];
      if (bias)  vv += bias[c];
      if (resid) vv += resid[(size_t)r * ldr + c];
      if (relu)  vv = fmaxf(vv, 0.f);
      C[(size_t)r * ldc + c] = vv;
    }
  }
}

// ---------------------------------------------------------------- QKV projection (per head, weird weight layout)
// out[(b*H+h)*T + t][e] = sum_d xn[bt][d] * W[l][h][d][e]
__global__ __launch_bounds__(256) void qkv_kernel(
    const float* __restrict__ xn,
    const float* __restrict__ Wq, const float* __restrict__ Wk, const float* __restrict__ Wv,
    float* __restrict__ qo, float* __restrict__ ko, float* __restrict__ vo,
    int layer)
{
  __shared__ float As[16][68];
  __shared__ float Bs[16][68];
  const int z = blockIdx.y;             // 0..23: mat*8 + h
  const int mat = z >> 3, h = z & 7;
  const float* W = (mat == 0 ? Wq : (mat == 1 ? Wk : Wv)) + ((size_t)(layer * H_ + h)) * D_ * HD_;
  float* out = (mat == 0 ? qo : (mat == 1 ? ko : vo)) + (size_t)h * T_ * HD_;
  const int tid = threadIdx.x;
  const int bm = blockIdx.x * 64;
  const int ty = tid >> 4, tx = tid & 15;
  const int ar = tid >> 2, ac4 = (tid & 3) * 4;
  const int br = tid >> 4, bc4 = (tid & 15) * 4;
  float acc[4][4] = {{0.f,0.f,0.f,0.f},{0.f,0.f,0.f,0.f},{0.f,0.f,0.f,0.f},{0.f,0.f,0.f,0.f}};

  for (int k0 = 0; k0 < D_; k0 += 16) {
    float4 av = *reinterpret_cast<const float4*>(xn + (size_t)(bm + ar) * D_ + k0 + ac4);
    float4 bv = *reinterpret_cast<const float4*>(W + (size_t)(k0 + br) * HD_ + bc4);
    __syncthreads();
    As[ac4+0][ar] = av.x; As[ac4+1][ar] = av.y; As[ac4+2][ar] = av.z; As[ac4+3][ar] = av.w;
    *reinterpret_cast<float4*>(&Bs[br][bc4]) = bv;
    __syncthreads();
    #pragma unroll
    for (int kk = 0; kk < 16; kk++) {
      const float4 a4 = *reinterpret_cast<const float4*>(&As[kk][ty*4]);
      const float4 b4 = *reinterpret_cast<const float4*>(&Bs[kk][tx*4]);
      acc[0][0] += a4.x*b4.x; acc[0][1] += a4.x*b4.y; acc[0][2] += a4.x*b4.z; acc[0][3] += a4.x*b4.w;
      acc[1][0] += a4.y*b4.x; acc[1][1] += a4.y*b4.y; acc[1][2] += a4.y*b4.z; acc[1][3] += a4.y*b4.w;
      acc[2][0] += a4.z*b4.x; acc[2][1] += a4.z*b4.y; acc[2][2] += a4.z*b4.z; acc[2][3] += a4.z*b4.w;
      acc[3][0] += a4.w*b4.x; acc[3][1] += a4.w*b4.y; acc[3][2] += a4.w*b4.z; acc[3][3] += a4.w*b4.w;
    }
  }
  #pragma unroll
  for (int i = 0; i < 4; i++) {
    int btr = bm + ty*4 + i;
    int b = btr >> 11;            // / T_
    int t = btr & (T_ - 1);
    #pragma unroll
    for (int j = 0; j < 4; j++) {
      out[((size_t)b * H_ * T_ + t) * HD_ + tx*4 + j] = acc[i][j];
    }
  }
}

// ---------------------------------------------------------------- flash attention (fp32, 64-query blocks)
__global__ __launch_bounds__(256) void attn_kernel(
    const float* __restrict__ q, const float* __restrict__ k,
    const float* __restrict__ v, float* __restrict__ o)
{
  __shared__ float QsT[64][68];  // QsT[d][r]
  __shared__ float KsT[64][68];  // KsT[d][c]
  __shared__ float Vs [64][68];  // Vs[c][e]
  __shared__ float SsT[64][68];  // SsT[c][r]
  __shared__ float mS[64], lS[64], aS[64];

  const int qb = blockIdx.x, bh = blockIdx.y;
  const int bb = bh >> 3, hh = bh & 7;
  const float* qp = q + ((size_t)bh * T_ + (size_t)qb * 64) * HD_;
  const float* kp = k + (size_t)bh * T_ * HD_;
  const float* vp = v + (size_t)bh * T_ * HD_;
  const int tid = threadIdx.x;
  const int ty = tid >> 4, tx = tid & 15;

  // load Q tile transposed
  #pragma unroll
  for (int rep = 0; rep < 4; rep++) {
    int fi = tid + rep * 256;
    int r = fi >> 4, c4 = (fi & 15) * 4;
    float4 t4 = *reinterpret_cast<const float4*>(qp + r * HD_ + c4);
    QsT[c4+0][r] = t4.x; QsT[c4+1][r] = t4.y; QsT[c4+2][r] = t4.z; QsT[c4+3][r] = t4.w;
  }
  if (tid < 64) { mS[tid] = -INFINITY; lS[tid] = 0.f; }
  float acc[4][4] = {{0.f,0.f,0.f,0.f},{0.f,0.f,0.f,0.f},{0.f,0.f,0.f,0.f},{0.f,0.f,0.f,0.f}};
  float s[4][4];

  for (int s0 = 0; s0 <= qb; s0++) {
    __syncthreads();  // protect K/V/S from previous iteration
    #pragma unroll
    for (int rep = 0; rep < 4; rep++) {
      int fi = tid + rep * 256;
      int r = fi >> 4, c4 = (fi & 15) * 4;
      float4 kt = *reinterpret_cast<const float4*>(kp + (size_t)(s0 * 64 + r) * HD_ + c4);
      float4 vt = *reinterpret_cast<const float4*>(vp + (size_t)(s0 * 64 + r) * HD_ + c4);
      KsT[c4+0][r] = kt.x; KsT[c4+1][r] = kt.y; KsT[c4+2][r] = kt.z; KsT[c4+3][r] = kt.w;
      Vs[r][c4+0] = vt.x; Vs[r][c4+1] = vt.y; Vs[r][c4+2] = vt.z; Vs[r][c4+3] = vt.w;
    }
    __syncthreads();
    // S = scale * Q @ K^T (4x4 per thread), masked
    #pragma unroll
    for (int i = 0; i < 4; i++)
      #pragma unroll
      for (int j = 0; j < 4; j++) s[i][j] = 0.f;
    for (int d = 0; d < 64; d++) {
      const float4 a4 = *reinterpret_cast<const float4*>(&QsT[d][ty*4]);
      const float4 b4 = *reinterpret_cast<const float4*>(&KsT[d][tx*4]);
      s[0][0] += a4.x*b4.x; s[0][1] += a4.x*b4.y; s[0][2] += a4.x*b4.z; s[0][3] += a4.x*b4.w;
      s[1][0] += a4.y*b4.x; s[1][1] += a4.y*b4.y; s[1][2] += a4.y*b4.z; s[1][3] += a4.y*b4.w;
      s[2][0] += a4.z*b4.x; s[2][1] += a4.z*b4.y; s[2][2] += a4.z*b4.z; s[2][3] += a4.z*b4.w;
      s[3][0] += a4.w*b4.x; s[3][1] += a4.w*b4.y; s[3][2] += a4.w*b4.z; s[3][3] += a4.w*b4.w;
    }
    const int diag = (s0 == qb);
    #pragma unroll
    for (int i = 0; i < 4; i++) {
      #pragma unroll
      for (int j = 0; j < 4; j++) {
        float sv = s[i][j] * SCALE_;
        if (diag && (tx*4 + j) > (ty*4 + i)) sv = -INFINITY;
        s[i][j] = sv;
        SsT[tx*4 + j][ty*4 + i] = sv;
      }
    }
    __syncthreads();
    // per-row running max
    if (tid < 64) {
      float pm = mS[tid];
      for (int c = 0; c < 64; c++) pm = fmaxf(pm, SsT[c][tid]);
      aS[tid] = expf(mS[tid] - pm);   // 0 on first block (exp(-inf))
      mS[tid] = pm;
    }
    __syncthreads();
    // rescale O, exponentiate S
    float mloc[4], al[4];
    #pragma unroll
    for (int i = 0; i < 4; i++) { mloc[i] = mS[ty*4 + i]; al[i] = aS[ty*4 + i]; }
    #pragma unroll
    for (int i = 0; i < 4; i++)
      #pragma unroll
      for (int j = 0; j < 4; j++) acc[i][j] *= al[i];
    #pragma unroll
    for (int i = 0; i < 4; i++) {
      #pragma unroll
      for (int j = 0; j < 4; j++) {
        float e = expf(s[i][j] - mloc[i]);   // masked -> exp(-inf)=0
        SsT[tx*4 + j][ty*4 + i] = e;
      }
    }
    __syncthreads();
    // per-row sum update
    if (tid < 64) {
      float sum = 0.f;
      for (int c = 0; c < 64; c++) sum += SsT[c][tid];
      lS[tid] = lS[tid] * aS[tid] + sum;
    }
    // O += P @ V  (reads only; D-phase above only reads SsT too)
    for (int c = 0; c < 64; c++) {
      const float4 p4 = *reinterpret_cast<const float4*>(&SsT[c][ty*4]);
      const float4 v4 = *reinterpret_cast<const float4*>(&Vs[c][tx*4]);
      acc[0][0] += p4.x*v4.x; acc[0][1] += p4.x*v4.y; acc[0][2] += p4.x*v4.z; acc[0][3] += p4.x*v4.w;
      acc[1][0] += p4.y*v4.x; acc[1][1] += p4.y*v4.y; acc[1][2] += p4.y*v4.z; acc[1][3] += p4.y*v4.w;
      acc[2][0] += p4.z*v4.x; acc[2][1] += p4.z*v4.y; acc[2][2] += p4.z*v4.z; acc[2][3] += p4.z*v4.w;
      acc[3][0] += p4.w*v4.x; acc[3][1] += p4.w*v4.y; acc[3][2] += p4.w*v4.z; acc[3][3] += p4.w*v4.w;
    }
  }
  __syncthreads();  // lS final
  #pragma unroll
  for (int i = 0; i < 4; i++) {
    int r = ty*4 + i;
    float inv = 1.0f / lS[r];
    int tg = qb * 64 + r;
    #pragma unroll
    for (int j = 0; j < 4; j++) {
      o[((size_t)bb * T_ + tg) * D_ + hh * HD_ + tx*4 + j] = acc[i][j] * inv;
    }
  }
}

// ---------------------------------------------------------------- loss
__global__ __launch_bounds__(256) void loss_row_kernel(
    const float* __restrict__ logits, const int* __restrict__ labels,
    float* __restrict__ rowloss)
{
  __shared__ float red[8];
  const int row = blockIdx.x;
  const float* lr = logits + (size_t)row * V_;
  const int tid = threadIdx.x, lane = tid & 63, wid = tid >> 6;
  float m = -INFINITY;
  for (int c = tid; c < V_; c += 256) m = fmaxf(m, lr[c]);
  #pragma unroll
  for (int off = 1; off < 64; off <<= 1) m = fmaxf(m, __shfl_xor(m, off));
  if (lane == 0) red[wid] = m;
  __syncthreads();
  m = fmaxf(fmaxf(red[0], red[1]), fmaxf(red[2], red[3]));
  float s = 0.f;
  for (int c = tid; c < V_; c += 256) s += expf(lr[c] - m);
  #pragma unroll
  for (int off = 1; off < 64; off <<= 1) s += __shfl_xor(s, off);
  if (lane == 0) red[4 + wid] = s;
  __syncthreads();
  if (tid == 0) {
    s = red[4] + red[5] + red[6] + red[7];
    rowloss[row] = lr[labels[row]] - m - logf(s);
  }
}

__global__ __launch_bounds__(256) void loss_final_kernel(
    const float* __restrict__ rowloss, float* __restrict__ out)
{
  __shared__ float red[4];
  const int tid = threadIdx.x, lane = tid & 63, wid = tid >> 6;
  float s = 0.f;
  for (int i = tid; i < BT_; i += 256) s += rowloss[i];
  #pragma unroll
  for (int off = 1; off < 64; off <<= 1) s += __shfl_xor(s, off);
  if (lane == 0) red[wid] = s;
  __syncthreads();
  if (tid == 0) out[0] = -(red[0] + red[1] + red[2] + red[3]) * (1.0f / BT_);
}

// ---------------------------------------------------------------- launch
extern "C" void kernel_launch(void* const* d_in, const int* in_sizes, int n_in,
                              void* d_out, int out_size, void* d_ws, size_t ws_size,
                              hipStream_t stream)
{
  (void)in_sizes; (void)n_in; (void)out_size; (void)ws_size;
  const int*   ids    = (const int*)d_in[0];
  const int*   labels = (const int*)d_in[1];
  const float* tok    = (const float*)d_in[2];
  const float* pos    = (const float*)d_in[3];
  const float* Wq     = (const float*)d_in[4];
  const float* Wk     = (const float*)d_in[5];
  const float* Wv     = (const float*)d_in[6];
  const float* Wo     = (const float*)d_in[7];
  const float* bo     = (const float*)d_in[8];
  const float* ln1g   = (const float*)d_in[9];
  const float* ln1b   = (const float*)d_in[10];
  const float* ln2g   = (const float*)d_in[11];
  const float* ln2b   = (const float*)d_in[12];
  const float* W1     = (const float*)d_in[13];
  const float* b1     = (const float*)d_in[14];
  const float* W2     = (const float*)d_in[15];
  const float* b2     = (const float*)d_in[16];
  const float* lnfg   = (const float*)d_in[17];
  const float* lnfb   = (const float*)d_in[18];
  const float* Wp     = (const float*)d_in[19];
  const float* bp     = (const float*)d_in[20];

  float* out = (float*)d_out;                 // logits [BT_*V_], then loss [1]
  float* ws  = (float*)d_ws;
  float* x   = ws;
  float* xn  = x  + (size_t)BT_ * D_;
  float* qb_ = xn + (size_t)BT_ * D_;
  float* kb_ = qb_ + (size_t)BT_ * D_;
  float* vb_ = kb_ + (size_t)BT_ * D_;
  float* ob_ = vb_ + (size_t)BT_ * D_;
  float* h1  = ob_ + (size_t)BT_ * D_;
  float* rowloss = h1 + (size_t)BT_ * 4 * D_;

  embed_kernel<<<BT_ * D_ / 4 / 256, 256, 0, stream>>>(ids, tok, pos, x);

  for (int l = 0; l < NL_; l++) {
    ln_kernel<<<BT_ / 4, 256, 0, stream>>>(x, ln1g + l * D_, ln1b + l * D_, xn);
    qkv_kernel<<<dim3(BT_ / 64, 24), 256, 0, stream>>>(xn, Wq, Wk, Wv, qb_, kb_, vb_, l);
    attn_kernel<<<dim3(T_ / 64, B_ * H_), 256, 0, stream>>>(qb_, kb_, vb_, ob_);
    gemm_kernel<<<dim3(BT_ / 64, D_ / 64), 256, 0, stream>>>(
        ob_, D_, Wo + (size_t)l * D_ * D_, D_, bo + l * D_, x, D_, x, D_, D_, 0);
    ln_kernel<<<BT_ / 4, 256, 0, stream>>>(x, ln2g + l * D_, ln2b + l * D_, xn);
    gemm_kernel<<<dim3(BT_ / 64, 4 * D_ / 64), 256, 0, stream>>>(
        xn, D_, W1 + (size_t)l * D_ * 4 * D_, 4 * D_, b1 + l * 4 * D_, nullptr, 0, h1, 4 * D_, D_, 1);
    gemm_kernel<<<dim3(BT_ / 64, D_ / 64), 256, 0, stream>>>(
        h1, 4 * D_, W2 + (size_t)l * 4 * D_ * D_, D_, b2 + l * D_, x, D_, x, D_, 4 * D_, 0);
  }

  ln_kernel<<<BT_ / 4, 256, 0, stream>>>(x, lnfg, lnfb, xn);
  gemm_kernel<<<dim3(BT_ / 64, V_ / 64), 256, 0, stream>>>(
      xn, D_, Wp, V_, bp, nullptr, 0, out, V_, D_, 0);

  loss_row_kernel<<<BT_, 256, 0, stream>>>(out, labels, rowloss);
  loss_final_kernel<<<1, 256, 0, stream>>>(rowloss, out + (size_t)BT_ * V_);
}

// Round 2
// 2673.197 us; speedup vs baseline: 1.8030x; 1.8030x over previous
//
#include <hip/hip_runtime.h>
#include <hip/hip_bf16.h>
#include <math.h>

#define B_ 2
#define T_ 2048
#define D_ 512
#define H_ 8
#define NL_ 4
#define V_ 32000
#define HD_ 64
#define BT_ (B_*T_)
#define EPS_ 1e-5f
#define SCALE_ 0.04419417382415922f  /* 1/sqrt(512) — source scales by D, not HD */

typedef __bf16 bf16x8 __attribute__((ext_vector_type(8)));
typedef float  f32x4  __attribute__((ext_vector_type(4)));

__device__ __forceinline__ unsigned short f2bf(float f) {
  union { float f; unsigned u; } v; v.f = f;
  unsigned r = v.u + 0x7fff + ((v.u >> 16) & 1);
  return (unsigned short)(r >> 16);
}

__device__ __forceinline__ void gl_lds16(const void* g, void* l) {
  __builtin_amdgcn_global_load_lds(
      (const __attribute__((address_space(1))) void*)g,
      (__attribute__((address_space(3))) void*)l, 16, 0, 0);
}

// ---------------------------------------------------------------- embed
__global__ __launch_bounds__(256) void embed_kernel(
    const int* __restrict__ ids, const float* __restrict__ tok,
    const float* __restrict__ pos, float* __restrict__ x)
{
  int i = blockIdx.x * 256 + threadIdx.x;
  int d4 = i & (D_/4 - 1);
  int bt = i >> 7;
  int t  = bt & (T_ - 1);
  const float4 a = reinterpret_cast<const float4*>(tok + (size_t)ids[bt] * D_)[d4];
  const float4 p = reinterpret_cast<const float4*>(pos + (size_t)t * D_)[d4];
  float4 r; r.x = a.x + p.x; r.y = a.y + p.y; r.z = a.z + p.z; r.w = a.w + p.w;
  reinterpret_cast<float4*>(x)[i] = r;
}

// ---------------------------------------------------------------- layernorm -> bf16 out
__global__ __launch_bounds__(256) void ln_kernel(
    const float* __restrict__ x, const float* __restrict__ g,
    const float* __restrict__ b, unsigned short* __restrict__ out)
{
  int row  = blockIdx.x * 4 + (threadIdx.x >> 6);
  int lane = threadIdx.x & 63;
  const float4* xr = reinterpret_cast<const float4*>(x + (size_t)row * D_);
  float4 v0 = xr[lane], v1 = xr[lane + 64];
  float s = v0.x + v0.y + v0.z + v0.w + v1.x + v1.y + v1.z + v1.w;
  float q = v0.x*v0.x + v0.y*v0.y + v0.z*v0.z + v0.w*v0.w
          + v1.x*v1.x + v1.y*v1.y + v1.z*v1.z + v1.w*v1.w;
  #pragma unroll
  for (int off = 1; off < 64; off <<= 1) {
    s += __shfl_xor(s, off);
    q += __shfl_xor(q, off);
  }
  float mean = s * (1.0f / D_);
  float var  = q * (1.0f / D_) - mean * mean;
  float rs   = rsqrtf(var + EPS_);
  const float4* g4 = reinterpret_cast<const float4*>(g);
  const float4* b4 = reinterpret_cast<const float4*>(b);
  float4 gv0 = g4[lane], gv1 = g4[lane + 64];
  float4 bv0 = b4[lane], bv1 = b4[lane + 64];
  ushort4 p0, p1;
  p0.x = f2bf((v0.x - mean) * rs * gv0.x + bv0.x);
  p0.y = f2bf((v0.y - mean) * rs * gv0.y + bv0.y);
  p0.z = f2bf((v0.z - mean) * rs * gv0.z + bv0.z);
  p0.w = f2bf((v0.w - mean) * rs * gv0.w + bv0.w);
  p1.x = f2bf((v1.x - mean) * rs * gv1.x + bv1.x);
  p1.y = f2bf((v1.y - mean) * rs * gv1.y + bv1.y);
  p1.z = f2bf((v1.z - mean) * rs * gv1.z + bv1.z);
  p1.w = f2bf((v1.w - mean) * rs * gv1.w + bv1.w);
  unsigned short* orow = out + (size_t)row * D_;
  *reinterpret_cast<ushort4*>(orow + lane * 4)       = p0;
  *reinterpret_cast<ushort4*>(orow + 256 + lane * 4) = p1;
}

// ---------------------------------------------------------------- transpose+cast fp32 [R][C] -> bf16 [C][R]
__global__ __launch_bounds__(256) void transpose_cast(
    const float* __restrict__ src, unsigned short* __restrict__ dst,
    int C, int R, long sstride, long dstride)
{
  src += (size_t)blockIdx.z * sstride;
  dst += (size_t)blockIdx.z * dstride;
  __shared__ float t[32][33];
  int r0 = blockIdx.x * 32, c0 = blockIdx.y * 32;
  int tx = threadIdx.x & 31, ty = threadIdx.x >> 5;
  #pragma unroll
  for (int i = 0; i < 4; i++)
    t[ty + i*8][tx] = src[(size_t)(r0 + ty + i*8) * C + c0 + tx];
  __syncthreads();
  #pragma unroll
  for (int i = 0; i < 4; i++)
    dst[(size_t)(c0 + ty + i*8) * R + r0 + tx] = f2bf(t[tx][ty + i*8]);
}

// WqkvT[l][mat*512 + h*64 + e][d] = W{q,k,v}[l][h][d][e]
__global__ __launch_bounds__(256) void qkvw_transpose(
    const float* __restrict__ Wq, const float* __restrict__ Wk,
    const float* __restrict__ Wv, unsigned short* __restrict__ dst)
{
  int z = blockIdx.z; int l = z / 24; int rem = z % 24; int mat = rem >> 3; int h = rem & 7;
  const float* W = (mat == 0 ? Wq : (mat == 1 ? Wk : Wv)) + ((size_t)(l * 8 + h)) * D_ * HD_;
  unsigned short* d = dst + ((size_t)l * 1536 + mat * 512 + h * 64) * D_;
  __shared__ float t[32][33];
  int d0 = blockIdx.x * 32, e0 = blockIdx.y * 32;
  int tx = threadIdx.x & 31, ty = threadIdx.x >> 5;
  #pragma unroll
  for (int i = 0; i < 4; i++)
    t[ty + i*8][tx] = W[(size_t)(d0 + ty + i*8) * HD_ + e0 + tx];
  __syncthreads();
  #pragma unroll
  for (int i = 0; i < 4; i++)
    d[(size_t)(e0 + ty + i*8) * D_ + d0 + tx] = f2bf(t[tx][ty + i*8]);
}

// ---------------------------------------------------------------- bf16 MFMA GEMM (m97 structure)
// C[M][N] = A[M][K](bf16) @ Bt[N][K](bf16)^T ; 128x128 tile, BK=64, 4 waves.
#define BM 128
#define BN 128
#define BKg 64

__global__ __launch_bounds__(256) void gemm_mfma(
    const unsigned short* __restrict__ A,
    const unsigned short* __restrict__ Bt,
    int K,
    const float* __restrict__ bias,
    const float* __restrict__ resid,
    float* __restrict__ outF,
    unsigned short* __restrict__ outH,
    int ldc, int relu)
{
  __shared__ __align__(16) unsigned short As[BM * BKg];
  __shared__ __align__(16) unsigned short Bs[BN * BKg];
  const int tid  = threadIdx.x;
  const int lane = tid & 63, wv = tid >> 6;
  const int bm = blockIdx.x * BM, bn = blockIdx.y * BN;
  const int m0w = (wv >> 1) * 64, n0w = (wv & 1) * 64;
  const int lr = lane & 15;
  const int kb = (lane >> 4) * 8;

  f32x4 acc[4][4];
  #pragma unroll
  for (int m = 0; m < 4; m++)
    #pragma unroll
    for (int n = 0; n < 4; n++)
      acc[m][n] = (f32x4){0.f, 0.f, 0.f, 0.f};

  for (int k0 = 0; k0 < K; k0 += BKg) {
    if (k0) __syncthreads();
    #pragma unroll
    for (int i = 0; i < 4; ++i) {
      int e = tid * 8 + i * 2048;
      int r = e >> 6, c = e & 63;
      gl_lds16(A  + (size_t)(bm + r) * K + k0 + c, (void*)(As + wv * 512 + i * 2048));
      gl_lds16(Bt + (size_t)(bn + r) * K + k0 + c, (void*)(Bs + wv * 512 + i * 2048));
    }
    __syncthreads();
    #pragma unroll
    for (int kk = 0; kk < 2; ++kk) {
      bf16x8 af[4], bfr[4];
      #pragma unroll
      for (int m = 0; m < 4; m++)
        af[m] = *reinterpret_cast<const bf16x8*>(&As[(m0w + m*16 + lr) * BKg + kk*32 + kb]);
      #pragma unroll
      for (int n = 0; n < 4; n++)
        bfr[n] = *reinterpret_cast<const bf16x8*>(&Bs[(n0w + n*16 + lr) * BKg + kk*32 + kb]);
      #pragma unroll
      for (int m = 0; m < 4; m++)
        #pragma unroll
        for (int n = 0; n < 4; n++)
          acc[m][n] = __builtin_amdgcn_mfma_f32_16x16x32_bf16(af[m], bfr[n], acc[m][n], 0, 0, 0);
    }
  }

  const int cr = (lane >> 4) * 4;
  const int cc = lane & 15;
  #pragma unroll
  for (int m = 0; m < 4; m++) {
    #pragma unroll
    for (int n = 0; n < 4; n++) {
      int row = bm + m0w + m*16 + cr;
      int col = bn + n0w + n*16 + cc;
      f32x4 a = acc[m][n];
      #pragma unroll
      for (int r = 0; r < 4; r++) {
        float v = a[r];
        if (bias)  v += bias[col];
        if (resid) v += resid[(size_t)(row + r) * ldc + col];
        if (relu)  v = fmaxf(v, 0.f);
        if (outF)  outF[(size_t)(row + r) * ldc + col] = v;
        if (outH)  outH[(size_t)(row + r) * ldc + col] = f2bf(v);
      }
    }
  }
}

// ---------------------------------------------------------------- flash attention (fp32), reads fused qkv, writes bf16
__global__ __launch_bounds__(256) void attn_kernel(
    const float* __restrict__ qkv, unsigned short* __restrict__ o)
{
  __shared__ float QsT[64][68];
  __shared__ float KsT[64][68];
  __shared__ float Vs [64][68];
  __shared__ float SsT[64][68];
  __shared__ float mS[64], lS[64], aS[64];

  const int qb = blockIdx.x, bh = blockIdx.y;
  const int bb = bh >> 3, hh = bh & 7;
  const float* qp = qkv + ((size_t)(bb * T_ + qb * 64)) * 1536 + hh * 64;
  const float* kp = qkv + ((size_t)bb * T_) * 1536 + 512  + hh * 64;
  const float* vp = qkv + ((size_t)bb * T_) * 1536 + 1024 + hh * 64;
  const int tid = threadIdx.x;
  const int ty = tid >> 4, tx = tid & 15;

  #pragma unroll
  for (int rep = 0; rep < 4; rep++) {
    int fi = tid + rep * 256;
    int r = fi >> 4, c4 = (fi & 15) * 4;
    float4 t4 = *reinterpret_cast<const float4*>(qp + (size_t)r * 1536 + c4);
    QsT[c4+0][r] = t4.x; QsT[c4+1][r] = t4.y; QsT[c4+2][r] = t4.z; QsT[c4+3][r] = t4.w;
  }
  if (tid < 64) { mS[tid] = -INFINITY; lS[tid] = 0.f; }
  float acc[4][4] = {{0.f,0.f,0.f,0.f},{0.f,0.f,0.f,0.f},{0.f,0.f,0.f,0.f},{0.f,0.f,0.f,0.f}};
  float s[4][4];

  for (int s0 = 0; s0 <= qb; s0++) {
    __syncthreads();
    #pragma unroll
    for (int rep = 0; rep < 4; rep++) {
      int fi = tid + rep * 256;
      int r = fi >> 4, c4 = (fi & 15) * 4;
      float4 kt = *reinterpret_cast<const float4*>(kp + (size_t)(s0 * 64 + r) * 1536 + c4);
      float4 vt = *reinterpret_cast<const float4*>(vp + (size_t)(s0 * 64 + r) * 1536 + c4);
      KsT[c4+0][r] = kt.x; KsT[c4+1][r] = kt.y; KsT[c4+2][r] = kt.z; KsT[c4+3][r] = kt.w;
      Vs[r][c4+0] = vt.x; Vs[r][c4+1] = vt.y; Vs[r][c4+2] = vt.z; Vs[r][c4+3] = vt.w;
    }
    __syncthreads();
    #pragma unroll
    for (int i = 0; i < 4; i++)
      #pragma unroll
      for (int j = 0; j < 4; j++) s[i][j] = 0.f;
    for (int d = 0; d < 64; d++) {
      const float4 a4 = *reinterpret_cast<const float4*>(&QsT[d][ty*4]);
      const float4 b4 = *reinterpret_cast<const float4*>(&KsT[d][tx*4]);
      s[0][0] += a4.x*b4.x; s[0][1] += a4.x*b4.y; s[0][2] += a4.x*b4.z; s[0][3] += a4.x*b4.w;
      s[1][0] += a4.y*b4.x; s[1][1] += a4.y*b4.y; s[1][2] += a4.y*b4.z; s[1][3] += a4.y*b4.w;
      s[2][0] += a4.z*b4.x; s[2][1] += a4.z*b4.y; s[2][2] += a4.z*b4.z; s[2][3] += a4.z*b4.w;
      s[3][0] += a4.w*b4.x; s[3][1] += a4.w*b4.y; s[3][2] += a4.w*b4.z; s[3][3] += a4.w*b4.w;
    }
    const int diag = (s0 == qb);
    #pragma unroll
    for (int i = 0; i < 4; i++) {
      #pragma unroll
      for (int j = 0; j < 4; j++) {
        float sv = s[i][j] * SCALE_;
        if (diag && (tx*4 + j) > (ty*4 + i)) sv = -INFINITY;
        s[i][j] = sv;
        SsT[tx*4 + j][ty*4 + i] = sv;
      }
    }
    __syncthreads();
    if (tid < 64) {
      float pm = mS[tid];
      for (int c = 0; c < 64; c++) pm = fmaxf(pm, SsT[c][tid]);
      aS[tid] = expf(mS[tid] - pm);
      mS[tid] = pm;
    }
    __syncthreads();
    float mloc[4], al[4];
    #pragma unroll
    for (int i = 0; i < 4; i++) { mloc[i] = mS[ty*4 + i]; al[i] = aS[ty*4 + i]; }
    #pragma unroll
    for (int i = 0; i < 4; i++)
      #pragma unroll
      for (int j = 0; j < 4; j++) acc[i][j] *= al[i];
    #pragma unroll
    for (int i = 0; i < 4; i++) {
      #pragma unroll
      for (int j = 0; j < 4; j++) {
        float e = expf(s[i][j] - mloc[i]);
        SsT[tx*4 + j][ty*4 + i] = e;
      }
    }
    __syncthreads();
    if (tid < 64) {
      float sum = 0.f;
      for (int c = 0; c < 64; c++) sum += SsT[c][tid];
      lS[tid] = lS[tid] * aS[tid] + sum;
    }
    for (int c = 0; c < 64; c++) {
      const float4 p4 = *reinterpret_cast<const float4*>(&SsT[c][ty*4]);
      const float4 v4 = *reinterpret_cast<const float4*>(&Vs[c][tx*4]);
      acc[0][0] += p4.x*v4.x; acc[0][1] += p4.x*v4.y; acc[0][2] += p4.x*v4.z; acc[0][3] += p4.x*v4.w;
      acc[1][0] += p4.y*v4.x; acc[1][1] += p4.y*v4.y; acc[1][2] += p4.y*v4.z; acc[1][3] += p4.y*v4.w;
      acc[2][0] += p4.z*v4.x; acc[2][1] += p4.z*v4.y; acc[2][2] += p4.z*v4.z; acc[2][3] += p4.z*v4.w;
      acc[3][0] += p4.w*v4.x; acc[3][1] += p4.w*v4.y; acc[3][2] += p4.w*v4.z; acc[3][3] += p4.w*v4.w;
    }
  }
  __syncthreads();
  #pragma unroll
  for (int i = 0; i < 4; i++) {
    int r = ty*4 + i;
    float inv = 1.0f / lS[r];
    int tg = qb * 64 + r;
    ushort4 pk;
    pk.x = f2bf(acc[i][0] * inv);
    pk.y = f2bf(acc[i][1] * inv);
    pk.z = f2bf(acc[i][2] * inv);
    pk.w = f2bf(acc[i][3] * inv);
    *reinterpret_cast<ushort4*>(&o[((size_t)(bb * T_ + tg)) * D_ + hh * HD_ + tx * 4]) = pk;
  }
}

// ---------------------------------------------------------------- loss
__global__ __launch_bounds__(256) void loss_row_kernel(
    const float* __restrict__ logits, const int* __restrict__ labels,
    float* __restrict__ rowloss)
{
  __shared__ float red[8];
  const int row = blockIdx.x;
  const float* lr = logits + (size_t)row * V_;
  const int tid = threadIdx.x, lane = tid & 63, wid = tid >> 6;
  float m = -INFINITY;
  for (int c = tid; c < V_; c += 256) m = fmaxf(m, lr[c]);
  #pragma unroll
  for (int off = 1; off < 64; off <<= 1) m = fmaxf(m, __shfl_xor(m, off));
  if (lane == 0) red[wid] = m;
  __syncthreads();
  m = fmaxf(fmaxf(red[0], red[1]), fmaxf(red[2], red[3]));
  float s = 0.f;
  for (int c = tid; c < V_; c += 256) s += expf(lr[c] - m);
  #pragma unroll
  for (int off = 1; off < 64; off <<= 1) s += __shfl_xor(s, off);
  if (lane == 0) red[4 + wid] = s;
  __syncthreads();
  if (tid == 0) {
    s = red[4] + red[5] + red[6] + red[7];
    rowloss[row] = lr[labels[row]] - m - logf(s);
  }
}

__global__ __launch_bounds__(256) void loss_final_kernel(
    const float* __restrict__ rowloss, float* __restrict__ out)
{
  __shared__ float red[4];
  const int tid = threadIdx.x, lane = tid & 63, wid = tid >> 6;
  float s = 0.f;
  for (int i = tid; i < BT_; i += 256) s += rowloss[i];
  #pragma unroll
  for (int off = 1; off < 64; off <<= 1) s += __shfl_xor(s, off);
  if (lane == 0) red[wid] = s;
  __syncthreads();
  if (tid == 0) out[0] = -(red[0] + red[1] + red[2] + red[3]) * (1.0f / BT_);
}

// ---------------------------------------------------------------- launch
extern "C" void kernel_launch(void* const* d_in, const int* in_sizes, int n_in,
                              void* d_out, int out_size, void* d_ws, size_t ws_size,
                              hipStream_t stream)
{
  (void)in_sizes; (void)n_in; (void)out_size; (void)ws_size;
  const int*   ids    = (const int*)d_in[0];
  const int*   labels = (const int*)d_in[1];
  const float* tok    = (const float*)d_in[2];
  const float* pos    = (const float*)d_in[3];
  const float* Wq     = (const float*)d_in[4];
  const float* Wk     = (const float*)d_in[5];
  const float* Wv     = (const float*)d_in[6];
  const float* Wo     = (const float*)d_in[7];
  const float* bo     = (const float*)d_in[8];
  const float* ln1g   = (const float*)d_in[9];
  const float* ln1b   = (const float*)d_in[10];
  const float* ln2g   = (const float*)d_in[11];
  const float* ln2b   = (const float*)d_in[12];
  const float* W1     = (const float*)d_in[13];
  const float* b1     = (const float*)d_in[14];
  const float* W2     = (const float*)d_in[15];
  const float* b2     = (const float*)d_in[16];
  const float* lnfg   = (const float*)d_in[17];
  const float* lnfb   = (const float*)d_in[18];
  const float* Wp     = (const float*)d_in[19];
  const float* bp     = (const float*)d_in[20];

  float* out = (float*)d_out;
  char* base = (char*)d_ws;
  // byte offsets (all 1 KB aligned); WpT aliases qkv/ob/h1 (dead at logits time)
  float*          x       = (float*)(base + 0);               //  8,388,608
  unsigned short* xn      = (unsigned short*)(base + 8388608);  //  4,194,304
  float*          rowloss = (float*)(base + 12582912);          //     16,384
  unsigned short* WqkvT   = (unsigned short*)(base + 12599296); //  6,291,456
  unsigned short* W1T     = (unsigned short*)(base + 18890752); //  8,388,608
  unsigned short* W2T     = (unsigned short*)(base + 27279360); //  8,388,608
  unsigned short* WoT     = (unsigned short*)(base + 35667968); //  2,097,152
  float*          qkv     = (float*)(base + 37765120);          // 25,165,824
  unsigned short* ob      = (unsigned short*)(base + 62930944); //  4,194,304
  unsigned short* h1      = (unsigned short*)(base + 67125248); // 16,777,216
  unsigned short* WpT     = (unsigned short*)(base + 37765120); // 32,768,000 (alias)

  embed_kernel<<<BT_ * D_ / 4 / 256, 256, 0, stream>>>(ids, tok, pos, x);

  // weight transforms (bf16, transposed to [N][K])
  qkvw_transpose<<<dim3(16, 2, 96), 256, 0, stream>>>(Wq, Wk, Wv, WqkvT);
  transpose_cast<<<dim3(16, 64, 4), 256, 0, stream>>>(W1, W1T, 2048, 512, 1048576, 1048576);
  transpose_cast<<<dim3(64, 16, 4), 256, 0, stream>>>(W2, W2T, 512, 2048, 1048576, 1048576);
  transpose_cast<<<dim3(16, 16, 4), 256, 0, stream>>>(Wo, WoT, 512, 512, 262144, 262144);

  for (int l = 0; l < NL_; l++) {
    ln_kernel<<<BT_ / 4, 256, 0, stream>>>(x, ln1g + l * D_, ln1b + l * D_, xn);
    gemm_mfma<<<dim3(BT_ / BM, 1536 / BN), 256, 0, stream>>>(
        xn, WqkvT + (size_t)l * 1536 * 512, 512, nullptr, nullptr, qkv, nullptr, 1536, 0);
    attn_kernel<<<dim3(T_ / 64, B_ * H_), 256, 0, stream>>>(qkv, ob);
    gemm_mfma<<<dim3(BT_ / BM, D_ / BN), 256, 0, stream>>>(
        ob, WoT + (size_t)l * 512 * 512, 512, bo + l * D_, x, x, nullptr, D_, 0);
    ln_kernel<<<BT_ / 4, 256, 0, stream>>>(x, ln2g + l * D_, ln2b + l * D_, xn);
    gemm_mfma<<<dim3(BT_ / BM, 4 * D_ / BN), 256, 0, stream>>>(
        xn, W1T + (size_t)l * 2048 * 512, 512, b1 + l * 4 * D_, nullptr, nullptr, h1, 4 * D_, 1);
    gemm_mfma<<<dim3(BT_ / BM, D_ / BN), 256, 0, stream>>>(
        h1, W2T + (size_t)l * 512 * 2048, 2048, b2 + l * D_, x, x, nullptr, D_, 0);
  }

  transpose_cast<<<dim3(16, 1000, 1), 256, 0, stream>>>(Wp, WpT, 32000, 512, 0, 0);
  ln_kernel<<<BT_ / 4, 256, 0, stream>>>(x, lnfg, lnfb, xn);
  gemm_mfma<<<dim3(BT_ / BM, V_ / BN), 256, 0, stream>>>(
      xn, WpT, 512, bp, nullptr, out, nullptr, V_, 0);

  loss_row_kernel<<<BT_, 256, 0, stream>>>(out, labels, rowloss);
  loss_final_kernel<<<1, 256, 0, stream>>>(rowloss, out + (size_t)BT_ * V_);
}

// Round 3
// 1659.523 us; speedup vs baseline: 2.9043x; 1.6108x over previous
//
#include <hip/hip_runtime.h>
#include <hip/hip_bf16.h>
#include <math.h>

#define B_ 2
#define T_ 2048
#define D_ 512
#define H_ 8
#define NL_ 4
#define V_ 32000
#define HD_ 64
#define BT_ (B_*T_)
#define EPS_ 1e-5f
#define SCALE_ 0.04419417382415922f  /* 1/sqrt(512) — source scales by D, not HD */
#define NEGBIG -1e30f

typedef __bf16 bf16x8 __attribute__((ext_vector_type(8)));
typedef float  f32x4  __attribute__((ext_vector_type(4)));

__device__ __forceinline__ unsigned short f2bf(float f) {
  union { float f; unsigned u; } v; v.f = f;
  unsigned r = v.u + 0x7fff + ((v.u >> 16) & 1);
  return (unsigned short)(r >> 16);
}

__device__ __forceinline__ void gl_lds16(const void* g, void* l) {
  __builtin_amdgcn_global_load_lds(
      (const __attribute__((address_space(1))) void*)g,
      (__attribute__((address_space(3))) void*)l, 16, 0, 0);
}

// ---------------------------------------------------------------- embed
__global__ __launch_bounds__(256) void embed_kernel(
    const int* __restrict__ ids, const float* __restrict__ tok,
    const float* __restrict__ pos, float* __restrict__ x)
{
  int i = blockIdx.x * 256 + threadIdx.x;
  int d4 = i & (D_/4 - 1);
  int bt = i >> 7;
  int t  = bt & (T_ - 1);
  const float4 a = reinterpret_cast<const float4*>(tok + (size_t)ids[bt] * D_)[d4];
  const float4 p = reinterpret_cast<const float4*>(pos + (size_t)t * D_)[d4];
  float4 r; r.x = a.x + p.x; r.y = a.y + p.y; r.z = a.z + p.z; r.w = a.w + p.w;
  reinterpret_cast<float4*>(x)[i] = r;
}

// ---------------------------------------------------------------- layernorm -> bf16 out
__global__ __launch_bounds__(256) void ln_kernel(
    const float* __restrict__ x, const float* __restrict__ g,
    const float* __restrict__ b, unsigned short* __restrict__ out)
{
  int row  = blockIdx.x * 4 + (threadIdx.x >> 6);
  int lane = threadIdx.x & 63;
  const float4* xr = reinterpret_cast<const float4*>(x + (size_t)row * D_);
  float4 v0 = xr[lane], v1 = xr[lane + 64];
  float s = v0.x + v0.y + v0.z + v0.w + v1.x + v1.y + v1.z + v1.w;
  float q = v0.x*v0.x + v0.y*v0.y + v0.z*v0.z + v0.w*v0.w
          + v1.x*v1.x + v1.y*v1.y + v1.z*v1.z + v1.w*v1.w;
  #pragma unroll
  for (int off = 1; off < 64; off <<= 1) {
    s += __shfl_xor(s, off);
    q += __shfl_xor(q, off);
  }
  float mean = s * (1.0f / D_);
  float var  = q * (1.0f / D_) - mean * mean;
  float rs   = rsqrtf(var + EPS_);
  const float4* g4 = reinterpret_cast<const float4*>(g);
  const float4* b4 = reinterpret_cast<const float4*>(b);
  float4 gv0 = g4[lane], gv1 = g4[lane + 64];
  float4 bv0 = b4[lane], bv1 = b4[lane + 64];
  ushort4 p0, p1;
  p0.x = f2bf((v0.x - mean) * rs * gv0.x + bv0.x);
  p0.y = f2bf((v0.y - mean) * rs * gv0.y + bv0.y);
  p0.z = f2bf((v0.z - mean) * rs * gv0.z + bv0.z);
  p0.w = f2bf((v0.w - mean) * rs * gv0.w + bv0.w);
  p1.x = f2bf((v1.x - mean) * rs * gv1.x + bv1.x);
  p1.y = f2bf((v1.y - mean) * rs * gv1.y + bv1.y);
  p1.z = f2bf((v1.z - mean) * rs * gv1.z + bv1.z);
  p1.w = f2bf((v1.w - mean) * rs * gv1.w + bv1.w);
  unsigned short* orow = out + (size_t)row * D_;
  *reinterpret_cast<ushort4*>(orow + lane * 4)       = p0;
  *reinterpret_cast<ushort4*>(orow + 256 + lane * 4) = p1;
}

// ---------------------------------------------------------------- transpose+cast fp32 [R][C] -> bf16 [C][R]
__global__ __launch_bounds__(256) void transpose_cast(
    const float* __restrict__ src, unsigned short* __restrict__ dst,
    int C, int R, long sstride, long dstride)
{
  src += (size_t)blockIdx.z * sstride;
  dst += (size_t)blockIdx.z * dstride;
  __shared__ float t[32][33];
  int r0 = blockIdx.x * 32, c0 = blockIdx.y * 32;
  int tx = threadIdx.x & 31, ty = threadIdx.x >> 5;
  #pragma unroll
  for (int i = 0; i < 4; i++)
    t[ty + i*8][tx] = src[(size_t)(r0 + ty + i*8) * C + c0 + tx];
  __syncthreads();
  #pragma unroll
  for (int i = 0; i < 4; i++)
    dst[(size_t)(c0 + ty + i*8) * R + r0 + tx] = f2bf(t[tx][ty + i*8]);
}

// WqkvT[l][mat*512 + h*64 + e][d] = W{q,k,v}[l][h][d][e]
__global__ __launch_bounds__(256) void qkvw_transpose(
    const float* __restrict__ Wq, const float* __restrict__ Wk,
    const float* __restrict__ Wv, unsigned short* __restrict__ dst)
{
  int z = blockIdx.z; int l = z / 24; int rem = z % 24; int mat = rem >> 3; int h = rem & 7;
  const float* W = (mat == 0 ? Wq : (mat == 1 ? Wk : Wv)) + ((size_t)(l * 8 + h)) * D_ * HD_;
  unsigned short* d = dst + ((size_t)l * 1536 + mat * 512 + h * 64) * D_;
  __shared__ float t[32][33];
  int d0 = blockIdx.x * 32, e0 = blockIdx.y * 32;
  int tx = threadIdx.x & 31, ty = threadIdx.x >> 5;
  #pragma unroll
  for (int i = 0; i < 4; i++)
    t[ty + i*8][tx] = W[(size_t)(d0 + ty + i*8) * HD_ + e0 + tx];
  __syncthreads();
  #pragma unroll
  for (int i = 0; i < 4; i++)
    d[(size_t)(e0 + ty + i*8) * D_ + d0 + tx] = f2bf(t[tx][ty + i*8]);
}

// ---------------------------------------------------------------- bf16 MFMA GEMM (m97 structure + XCD swizzle)
#define BM 128
#define BN 128
#define BKg 64

__global__ __launch_bounds__(256) void gemm_mfma(
    const unsigned short* __restrict__ A,
    const unsigned short* __restrict__ Bt,
    int K,
    const float* __restrict__ bias,
    const float* __restrict__ resid,
    float* __restrict__ outF,
    unsigned short* __restrict__ outH,
    int ldc, int relu)
{
  __shared__ __align__(16) unsigned short As[BM * BKg];
  __shared__ __align__(16) unsigned short Bs[BN * BKg];
  const int tid  = threadIdx.x;
  const int lane = tid & 63, wv = tid >> 6;

  // XCD-aware bijective block swizzle (grids are always a multiple of 8 here)
  const int gx = gridDim.x;
  int id = blockIdx.y * gx + blockIdx.x;
  const int nwg = gx * gridDim.y;
  if ((nwg & 7) == 0) {
    const int q = nwg >> 3;
    id = (id & 7) * q + (id >> 3);
  }
  const int bm = (id % gx) * BM, bn = (id / gx) * BN;

  const int m0w = (wv >> 1) * 64, n0w = (wv & 1) * 64;
  const int lr = lane & 15;
  const int kb = (lane >> 4) * 8;

  f32x4 acc[4][4];
  #pragma unroll
  for (int m = 0; m < 4; m++)
    #pragma unroll
    for (int n = 0; n < 4; n++)
      acc[m][n] = (f32x4){0.f, 0.f, 0.f, 0.f};

  for (int k0 = 0; k0 < K; k0 += BKg) {
    if (k0) __syncthreads();
    #pragma unroll
    for (int i = 0; i < 4; ++i) {
      int e = tid * 8 + i * 2048;
      int r = e >> 6, c = e & 63;
      gl_lds16(A  + (size_t)(bm + r) * K + k0 + c, (void*)(As + wv * 512 + i * 2048));
      gl_lds16(Bt + (size_t)(bn + r) * K + k0 + c, (void*)(Bs + wv * 512 + i * 2048));
    }
    __syncthreads();
    #pragma unroll
    for (int kk = 0; kk < 2; ++kk) {
      bf16x8 af[4], bfr[4];
      #pragma unroll
      for (int m = 0; m < 4; m++)
        af[m] = *reinterpret_cast<const bf16x8*>(&As[(m0w + m*16 + lr) * BKg + kk*32 + kb]);
      #pragma unroll
      for (int n = 0; n < 4; n++)
        bfr[n] = *reinterpret_cast<const bf16x8*>(&Bs[(n0w + n*16 + lr) * BKg + kk*32 + kb]);
      #pragma unroll
      for (int m = 0; m < 4; m++)
        #pragma unroll
        for (int n = 0; n < 4; n++)
          acc[m][n] = __builtin_amdgcn_mfma_f32_16x16x32_bf16(af[m], bfr[n], acc[m][n], 0, 0, 0);
    }
  }

  const int cr = (lane >> 4) * 4;
  const int cc = lane & 15;
  #pragma unroll
  for (int m = 0; m < 4; m++) {
    #pragma unroll
    for (int n = 0; n < 4; n++) {
      int row = bm + m0w + m*16 + cr;
      int col = bn + n0w + n*16 + cc;
      f32x4 a = acc[m][n];
      #pragma unroll
      for (int r = 0; r < 4; r++) {
        float v = a[r];
        if (bias)  v += bias[col];
        if (resid) v += resid[(size_t)(row + r) * ldc + col];
        if (relu)  v = fmaxf(v, 0.f);
        if (outF)  outF[(size_t)(row + r) * ldc + col] = v;
        if (outH)  outH[(size_t)(row + r) * ldc + col] = f2bf(v);
      }
    }
  }
}

// ---------------------------------------------------------------- MFMA flash attention (bf16 in/out)
// 64 q-rows per block, 4 waves (16 rows each), KV tiles of 64.
// LDS layouts use XOR swizzle: idx(row,col) = row*64 + (((col>>3)^(row&7))<<3) + (col&7)
__global__ __launch_bounds__(256) void attn_mfma(
    const unsigned short* __restrict__ qkv,  // bf16 [B*T][1536]
    unsigned short* __restrict__ o)          // bf16 [B*T][512]
{
  __shared__ __align__(16) unsigned short Ks[64*64];     // [kv][hd] swizzled
  __shared__ __align__(16) unsigned short Vt[64*64];     // [hd][kv] swizzled
  __shared__ __align__(16) unsigned short Ps[4][16*64];  // per-wave [q16][kv] swizzled

  const int qb = (int)gridDim.x - 1 - (int)blockIdx.x;   // heavy blocks first
  const int bh = blockIdx.y, bb = bh >> 3, hh = bh & 7;
  const int tid = threadIdx.x, lane = tid & 63, wv = tid >> 6;
  const int lr = lane & 15, g = lane >> 4;

  const unsigned short* qp = qkv + ((size_t)(bb*T_ + qb*64))*1536 + hh*64;
  const unsigned short* kp = qkv + ((size_t)bb*T_)*1536 + 512  + hh*64;
  const unsigned short* vp = qkv + ((size_t)bb*T_)*1536 + 1024 + hh*64;

  // Q A-fragments in registers: row = wv*16+lr, k-chunk = kk*32 + g*8
  bf16x8 qf[2];
  qf[0] = *reinterpret_cast<const bf16x8*>(qp + (size_t)(wv*16 + lr)*1536 + g*8);
  qf[1] = *reinterpret_cast<const bf16x8*>(qp + (size_t)(wv*16 + lr)*1536 + 32 + g*8);

  f32x4 ov[4];
  #pragma unroll
  for (int n = 0; n < 4; n++) ov[n] = (f32x4){0.f, 0.f, 0.f, 0.f};
  float mrow[4] = {NEGBIG, NEGBIG, NEGBIG, NEGBIG};
  float lrow[4] = {0.f, 0.f, 0.f, 0.f};

  for (int s0 = 0; s0 <= qb; ++s0) {
    __syncthreads();  // all reads of Ks/Vt from previous tile done
    // --- stage K via global_load_lds with pre-swizzled global source
    #pragma unroll
    for (int i = 0; i < 2; i++) {
      int kv = i*32 + wv*8 + (lane >> 3);
      int hb = (lane & 7) ^ (lane >> 3);       // = (chunk&7) ^ (kv&7)
      gl_lds16(kp + (size_t)(s0*64 + kv)*1536 + hb*8,
               (void*)(Ks + i*2048 + wv*512));
    }
    // --- stage V transposed (reg-staged, swizzled writes: conflict-light)
    #pragma unroll
    for (int it = 0; it < 2; it++) {
      int c0 = wv*8 + it*32;                   // hd chunk (multiple of 8)
      union { uint4 v; unsigned short e[8]; } uv;
      uv.v = *reinterpret_cast<const uint4*>(vp + (size_t)(s0*64 + lane)*1536 + c0);
      #pragma unroll
      for (int j = 0; j < 8; j++)
        Vt[(c0 + j)*64 + (((lane >> 3) ^ j) << 3) + (lane & 7)] = uv.e[j];
    }
    __syncthreads();

    // --- S = Q @ K^T
    f32x4 sf[4];
    #pragma unroll
    for (int n = 0; n < 4; n++) sf[n] = (f32x4){0.f, 0.f, 0.f, 0.f};
    #pragma unroll
    for (int kk = 0; kk < 2; kk++) {
      #pragma unroll
      for (int n = 0; n < 4; n++) {
        const bf16x8 kf = *reinterpret_cast<const bf16x8*>(
            &Ks[(n*16 + lr)*64 + (((kk*4 + g) ^ (lr & 7)) << 3)]);
        sf[n] = __builtin_amdgcn_mfma_f32_16x16x32_bf16(qf[kk], kf, sf[n], 0, 0, 0);
      }
    }

    // --- scale + causal mask (diag tile only; earlier tiles fully valid)
    const int diag = (s0 == qb);
    float sv[4][4];
    #pragma unroll
    for (int n = 0; n < 4; n++)
      #pragma unroll
      for (int r = 0; r < 4; r++) {
        float xv = sf[n][r] * SCALE_;
        if (diag && (n*16 + lr) > (wv*16 + g*4 + r)) xv = NEGBIG;
        sv[n][r] = xv;
      }

    // --- online softmax (rows live in 16-lane groups; shfl_xor 1,2,4,8)
    float aa[4];
    #pragma unroll
    for (int r = 0; r < 4; r++) {
      float pm = fmaxf(fmaxf(sv[0][r], sv[1][r]), fmaxf(sv[2][r], sv[3][r]));
      pm = fmaxf(pm, __shfl_xor(pm, 1));
      pm = fmaxf(pm, __shfl_xor(pm, 2));
      pm = fmaxf(pm, __shfl_xor(pm, 4));
      pm = fmaxf(pm, __shfl_xor(pm, 8));
      float mn = fmaxf(mrow[r], pm);
      aa[r] = __expf(mrow[r] - mn);
      mrow[r] = mn;
    }
    float rs[4] = {0.f, 0.f, 0.f, 0.f};
    #pragma unroll
    for (int n = 0; n < 4; n++)
      #pragma unroll
      for (int r = 0; r < 4; r++) {
        float p = __expf(sv[n][r] - mrow[r]);
        rs[r] += p;
        // P[q = g*4+r][kv = n*16+lr], swizzled
        Ps[wv][(g*4 + r)*64 + ((((n << 1) + (lr >> 3)) ^ ((g*4 + r) & 7)) << 3) + (lr & 7)] = f2bf(p);
      }
    #pragma unroll
    for (int r = 0; r < 4; r++) {
      float s = rs[r];
      s += __shfl_xor(s, 1); s += __shfl_xor(s, 2);
      s += __shfl_xor(s, 4); s += __shfl_xor(s, 8);
      lrow[r] = lrow[r]*aa[r] + s;
    }
    #pragma unroll
    for (int n = 0; n < 4; n++)
      #pragma unroll
      for (int r = 0; r < 4; r++)
        ov[n][r] *= aa[r];

    // --- O += P @ V   (Ps write->read same wave: compiler orders via lgkmcnt)
    #pragma unroll
    for (int kk = 0; kk < 2; kk++) {
      const bf16x8 pf = *reinterpret_cast<const bf16x8*>(
          &Ps[wv][lr*64 + (((kk*4 + g) ^ (lr & 7)) << 3)]);
      #pragma unroll
      for (int n = 0; n < 4; n++) {
        const bf16x8 vf = *reinterpret_cast<const bf16x8*>(
            &Vt[(n*16 + lr)*64 + (((kk*4 + g) ^ (lr & 7)) << 3)]);
        ov[n] = __builtin_amdgcn_mfma_f32_16x16x32_bf16(pf, vf, ov[n], 0, 0, 0);
      }
    }
  }

  // --- epilogue: normalize, write bf16
  #pragma unroll
  for (int r = 0; r < 4; r++) {
    float inv = 1.0f / lrow[r];
    size_t row = (size_t)(bb*T_ + qb*64 + wv*16 + g*4 + r);
    #pragma unroll
    for (int n = 0; n < 4; n++)
      o[row*D_ + hh*64 + n*16 + lr] = f2bf(ov[n][r] * inv);
  }
}

// ---------------------------------------------------------------- loss
__global__ __launch_bounds__(256) void loss_row_kernel(
    const float* __restrict__ logits, const int* __restrict__ labels,
    float* __restrict__ rowloss)
{
  __shared__ float red[8];
  const int row = blockIdx.x;
  const float* lr = logits + (size_t)row * V_;
  const int tid = threadIdx.x, lane = tid & 63, wid = tid >> 6;
  float m = -INFINITY;
  for (int c = tid; c < V_; c += 256) m = fmaxf(m, lr[c]);
  #pragma unroll
  for (int off = 1; off < 64; off <<= 1) m = fmaxf(m, __shfl_xor(m, off));
  if (lane == 0) red[wid] = m;
  __syncthreads();
  m = fmaxf(fmaxf(red[0], red[1]), fmaxf(red[2], red[3]));
  float s = 0.f;
  for (int c = tid; c < V_; c += 256) s += expf(lr[c] - m);
  #pragma unroll
  for (int off = 1; off < 64; off <<= 1) s += __shfl_xor(s, off);
  if (lane == 0) red[4 + wid] = s;
  __syncthreads();
  if (tid == 0) {
    s = red[4] + red[5] + red[6] + red[7];
    rowloss[row] = lr[labels[row]] - m - logf(s);
  }
}

__global__ __launch_bounds__(256) void loss_final_kernel(
    const float* __restrict__ rowloss, float* __restrict__ out)
{
  __shared__ float red[4];
  const int tid = threadIdx.x, lane = tid & 63, wid = tid >> 6;
  float s = 0.f;
  for (int i = tid; i < BT_; i += 256) s += rowloss[i];
  #pragma unroll
  for (int off = 1; off < 64; off <<= 1) s += __shfl_xor(s, off);
  if (lane == 0) red[wid] = s;
  __syncthreads();
  if (tid == 0) out[0] = -(red[0] + red[1] + red[2] + red[3]) * (1.0f / BT_);
}

// ---------------------------------------------------------------- launch
extern "C" void kernel_launch(void* const* d_in, const int* in_sizes, int n_in,
                              void* d_out, int out_size, void* d_ws, size_t ws_size,
                              hipStream_t stream)
{
  (void)in_sizes; (void)n_in; (void)out_size; (void)ws_size;
  const int*   ids    = (const int*)d_in[0];
  const int*   labels = (const int*)d_in[1];
  const float* tok    = (const float*)d_in[2];
  const float* pos    = (const float*)d_in[3];
  const float* Wq     = (const float*)d_in[4];
  const float* Wk     = (const float*)d_in[5];
  const float* Wv     = (const float*)d_in[6];
  const float* Wo     = (const float*)d_in[7];
  const float* bo     = (const float*)d_in[8];
  const float* ln1g   = (const float*)d_in[9];
  const float* ln1b   = (const float*)d_in[10];
  const float* ln2g   = (const float*)d_in[11];
  const float* ln2b   = (const float*)d_in[12];
  const float* W1     = (const float*)d_in[13];
  const float* b1     = (const float*)d_in[14];
  const float* W2     = (const float*)d_in[15];
  const float* b2     = (const float*)d_in[16];
  const float* lnfg   = (const float*)d_in[17];
  const float* lnfb   = (const float*)d_in[18];
  const float* Wp     = (const float*)d_in[19];
  const float* bp     = (const float*)d_in[20];

  float* out = (float*)d_out;
  char* base = (char*)d_ws;
  float*          x       = (float*)(base + 0);                 //  8,388,608
  unsigned short* xn      = (unsigned short*)(base + 8388608);  //  4,194,304
  float*          rowloss = (float*)(base + 12582912);          //     16,384
  unsigned short* WqkvT   = (unsigned short*)(base + 12599296); //  6,291,456
  unsigned short* W1T     = (unsigned short*)(base + 18890752); //  8,388,608
  unsigned short* W2T     = (unsigned short*)(base + 27279360); //  8,388,608
  unsigned short* WoT     = (unsigned short*)(base + 35667968); //  2,097,152
  unsigned short* qkvh    = (unsigned short*)(base + 37765120); // 12,582,912
  unsigned short* ob      = (unsigned short*)(base + 50348032); //  4,194,304
  unsigned short* h1      = (unsigned short*)(base + 54542336); // 16,777,216
  unsigned short* WpT     = (unsigned short*)(base + 37765120); // 32,768,000 (alias: dead at logits time)

  embed_kernel<<<BT_ * D_ / 4 / 256, 256, 0, stream>>>(ids, tok, pos, x);

  qkvw_transpose<<<dim3(16, 2, 96), 256, 0, stream>>>(Wq, Wk, Wv, WqkvT);
  transpose_cast<<<dim3(16, 64, 4), 256, 0, stream>>>(W1, W1T, 2048, 512, 1048576, 1048576);
  transpose_cast<<<dim3(64, 16, 4), 256, 0, stream>>>(W2, W2T, 512, 2048, 1048576, 1048576);
  transpose_cast<<<dim3(16, 16, 4), 256, 0, stream>>>(Wo, WoT, 512, 512, 262144, 262144);

  for (int l = 0; l < NL_; l++) {
    ln_kernel<<<BT_ / 4, 256, 0, stream>>>(x, ln1g + l * D_, ln1b + l * D_, xn);
    gemm_mfma<<<dim3(BT_ / BM, 1536 / BN), 256, 0, stream>>>(
        xn, WqkvT + (size_t)l * 1536 * 512, 512, nullptr, nullptr, nullptr, qkvh, 1536, 0);
    attn_mfma<<<dim3(T_ / 64, B_ * H_), 256, 0, stream>>>(qkvh, ob);
    gemm_mfma<<<dim3(BT_ / BM, D_ / BN), 256, 0, stream>>>(
        ob, WoT + (size_t)l * 512 * 512, 512, bo + l * D_, x, x, nullptr, D_, 0);
    ln_kernel<<<BT_ / 4, 256, 0, stream>>>(x, ln2g + l * D_, ln2b + l * D_, xn);
    gemm_mfma<<<dim3(BT_ / BM, 4 * D_ / BN), 256, 0, stream>>>(
        xn, W1T + (size_t)l * 2048 * 512, 512, b1 + l * 4 * D_, nullptr, nullptr, h1, 4 * D_, 1);
    gemm_mfma<<<dim3(BT_ / BM, D_ / BN), 256, 0, stream>>>(
        h1, W2T + (size_t)l * 512 * 2048, 2048, b2 + l * D_, x, x, nullptr, D_, 0);
  }

  transpose_cast<<<dim3(16, 1000, 1), 256, 0, stream>>>(Wp, WpT, 32000, 512, 0, 0);
  ln_kernel<<<BT_ / 4, 256, 0, stream>>>(x, lnfg, lnfb, xn);
  gemm_mfma<<<dim3(BT_ / BM, V_ / BN), 256, 0, stream>>>(
      xn, WpT, 512, bp, nullptr, out, nullptr, V_, 0);

  loss_row_kernel<<<BT_, 256, 0, stream>>>(out, labels, rowloss);
  loss_final_kernel<<<1, 256, 0, stream>>>(rowloss, out + (size_t)BT_ * V_);
}

// Round 4
// 1521.965 us; speedup vs baseline: 3.1668x; 1.0904x over previous
//
#include <hip/hip_runtime.h>
#include <hip/hip_bf16.h>
#include <math.h>

#define B_ 2
#define T_ 2048
#define D_ 512
#define H_ 8
#define NL_ 4
#define V_ 32000
#define HD_ 64
#define BT_ (B_*T_)
#define EPS_ 1e-5f
#define SCALE_ 0.04419417382415922f  /* 1/sqrt(512) — source scales by D, not HD */
#define NEGBIG -1e30f

typedef __bf16 bf16x8 __attribute__((ext_vector_type(8)));
typedef float  f32x4  __attribute__((ext_vector_type(4)));

__device__ __forceinline__ unsigned short f2bf(float f) {
  union { float f; unsigned u; } v; v.f = f;
  unsigned r = v.u + 0x7fff + ((v.u >> 16) & 1);
  return (unsigned short)(r >> 16);
}

__device__ __forceinline__ void gl_lds16(const void* g, void* l) {
  __builtin_amdgcn_global_load_lds(
      (const __attribute__((address_space(1))) void*)g,
      (__attribute__((address_space(3))) void*)l, 16, 0, 0);
}

// ---------------------------------------------------------------- embed
__global__ __launch_bounds__(256) void embed_kernel(
    const int* __restrict__ ids, const float* __restrict__ tok,
    const float* __restrict__ pos, float* __restrict__ x)
{
  int i = blockIdx.x * 256 + threadIdx.x;
  int d4 = i & (D_/4 - 1);
  int bt = i >> 7;
  int t  = bt & (T_ - 1);
  const float4 a = reinterpret_cast<const float4*>(tok + (size_t)ids[bt] * D_)[d4];
  const float4 p = reinterpret_cast<const float4*>(pos + (size_t)t * D_)[d4];
  float4 r; r.x = a.x + p.x; r.y = a.y + p.y; r.z = a.z + p.z; r.w = a.w + p.w;
  reinterpret_cast<float4*>(x)[i] = r;
}

// ---------------------------------------------------------------- layernorm -> bf16 out
__global__ __launch_bounds__(256) void ln_kernel(
    const float* __restrict__ x, const float* __restrict__ g,
    const float* __restrict__ b, unsigned short* __restrict__ out)
{
  int row  = blockIdx.x * 4 + (threadIdx.x >> 6);
  int lane = threadIdx.x & 63;
  const float4* xr = reinterpret_cast<const float4*>(x + (size_t)row * D_);
  float4 v0 = xr[lane], v1 = xr[lane + 64];
  float s = v0.x + v0.y + v0.z + v0.w + v1.x + v1.y + v1.z + v1.w;
  float q = v0.x*v0.x + v0.y*v0.y + v0.z*v0.z + v0.w*v0.w
          + v1.x*v1.x + v1.y*v1.y + v1.z*v1.z + v1.w*v1.w;
  #pragma unroll
  for (int off = 1; off < 64; off <<= 1) {
    s += __shfl_xor(s, off);
    q += __shfl_xor(q, off);
  }
  float mean = s * (1.0f / D_);
  float var  = q * (1.0f / D_) - mean * mean;
  float rs   = rsqrtf(var + EPS_);
  const float4* g4 = reinterpret_cast<const float4*>(g);
  const float4* b4 = reinterpret_cast<const float4*>(b);
  float4 gv0 = g4[lane], gv1 = g4[lane + 64];
  float4 bv0 = b4[lane], bv1 = b4[lane + 64];
  ushort4 p0, p1;
  p0.x = f2bf((v0.x - mean) * rs * gv0.x + bv0.x);
  p0.y = f2bf((v0.y - mean) * rs * gv0.y + bv0.y);
  p0.z = f2bf((v0.z - mean) * rs * gv0.z + bv0.z);
  p0.w = f2bf((v0.w - mean) * rs * gv0.w + bv0.w);
  p1.x = f2bf((v1.x - mean) * rs * gv1.x + bv1.x);
  p1.y = f2bf((v1.y - mean) * rs * gv1.y + bv1.y);
  p1.z = f2bf((v1.z - mean) * rs * gv1.z + bv1.z);
  p1.w = f2bf((v1.w - mean) * rs * gv1.w + bv1.w);
  unsigned short* orow = out + (size_t)row * D_;
  *reinterpret_cast<ushort4*>(orow + lane * 4)       = p0;
  *reinterpret_cast<ushort4*>(orow + 256 + lane * 4) = p1;
}

// ---------------------------------------------------------------- transpose+cast fp32 [R][C] -> bf16 [C][R]
__global__ __launch_bounds__(256) void transpose_cast(
    const float* __restrict__ src, unsigned short* __restrict__ dst,
    int C, int R, long sstride, long dstride)
{
  src += (size_t)blockIdx.z * sstride;
  dst += (size_t)blockIdx.z * dstride;
  __shared__ float t[32][33];
  int r0 = blockIdx.x * 32, c0 = blockIdx.y * 32;
  int tx = threadIdx.x & 31, ty = threadIdx.x >> 5;
  #pragma unroll
  for (int i = 0; i < 4; i++)
    t[ty + i*8][tx] = src[(size_t)(r0 + ty + i*8) * C + c0 + tx];
  __syncthreads();
  #pragma unroll
  for (int i = 0; i < 4; i++)
    dst[(size_t)(c0 + ty + i*8) * R + r0 + tx] = f2bf(t[tx][ty + i*8]);
}

// WqkvT[l][mat*512 + h*64 + e][d] = W{q,k,v}[l][h][d][e]
__global__ __launch_bounds__(256) void qkvw_transpose(
    const float* __restrict__ Wq, const float* __restrict__ Wk,
    const float* __restrict__ Wv, unsigned short* __restrict__ dst)
{
  int z = blockIdx.z; int l = z / 24; int rem = z % 24; int mat = rem >> 3; int h = rem & 7;
  const float* W = (mat == 0 ? Wq : (mat == 1 ? Wk : Wv)) + ((size_t)(l * 8 + h)) * D_ * HD_;
  unsigned short* d = dst + ((size_t)l * 1536 + mat * 512 + h * 64) * D_;
  __shared__ float t[32][33];
  int d0 = blockIdx.x * 32, e0 = blockIdx.y * 32;
  int tx = threadIdx.x & 31, ty = threadIdx.x >> 5;
  #pragma unroll
  for (int i = 0; i < 4; i++)
    t[ty + i*8][tx] = W[(size_t)(d0 + ty + i*8) * HD_ + e0 + tx];
  __syncthreads();
  #pragma unroll
  for (int i = 0; i < 4; i++)
    d[(size_t)(e0 + ty + i*8) * D_ + d0 + tx] = f2bf(t[tx][ty + i*8]);
}

// ---------------------------------------------------------------- bf16 MFMA GEMM
// 128x128 tile, BK=64, 4 waves. Double-buffered LDS, counted vmcnt, raw
// barriers, XOR-swizzled LDS (pre-swizzled global source + swizzled ds_read).
#define BM 128
#define BN 128
#define BKg 64

__global__ __launch_bounds__(256) void gemm_mfma(
    const unsigned short* __restrict__ A,
    const unsigned short* __restrict__ Bt,
    int K,
    const float* __restrict__ bias,
    const float* __restrict__ resid,
    float* __restrict__ outF,
    unsigned short* __restrict__ outH,
    int ldc, int relu)
{
  __shared__ __align__(16) unsigned short As[2][BM * BKg];
  __shared__ __align__(16) unsigned short Bs[2][BN * BKg];
  const int tid  = threadIdx.x;
  const int lane = tid & 63, wv = tid >> 6;

  // XCD-aware bijective block swizzle (grids here always have nwg%8==0)
  const int gx = gridDim.x;
  int id = blockIdx.y * gx + blockIdx.x;
  const int nwg = gx * gridDim.y;
  if ((nwg & 7) == 0) {
    const int q = nwg >> 3;
    id = (id & 7) * q + (id >> 3);
  }
  const int bm = (id % gx) * BM, bn = (id / gx) * BN;

  const int m0w = (wv >> 1) * 64, n0w = (wv & 1) * 64;
  const int lr = lane & 15;
  const int g  = lane >> 4;

  // staging coords: lane covers row r = i*32 + wv*8 + (lane>>3), swizzled chunk
  const int srow = wv * 8 + (lane >> 3);
  const int schk = (lane & 7) ^ ((lane >> 3) & 7);   // pre-swizzled source chunk
  const unsigned short* Ab = A  + (size_t)(bm + srow) * K + schk * 8;
  const unsigned short* Bb = Bt + (size_t)(bn + srow) * K + schk * 8;
  unsigned short* AsD[2] = { As[0] + wv * 512, As[1] + wv * 512 };
  unsigned short* BsD[2] = { Bs[0] + wv * 512, Bs[1] + wv * 512 };

#define STAGE(kof, bf)                                                     \
  {                                                                        \
    _Pragma("unroll")                                                      \
    for (int i_ = 0; i_ < 4; ++i_) {                                       \
      gl_lds16(Ab + (size_t)(i_ * 32) * K + (kof), AsD[bf] + i_ * 2048);   \
      gl_lds16(Bb + (size_t)(i_ * 32) * K + (kof), BsD[bf] + i_ * 2048);   \
    }                                                                      \
  }

  f32x4 acc[4][4];
  #pragma unroll
  for (int m = 0; m < 4; m++)
    #pragma unroll
    for (int n = 0; n < 4; n++)
      acc[m][n] = (f32x4){0.f, 0.f, 0.f, 0.f};

  const int nt = K >> 6;
  STAGE(0, 0);

  for (int t = 0; t < nt; ++t) {
    __builtin_amdgcn_sched_barrier(0);
    if (t + 1 < nt) {
      STAGE((t + 1) << 6, (t + 1) & 1);
      asm volatile("s_waitcnt vmcnt(8)" ::: "memory");
    } else {
      asm volatile("s_waitcnt vmcnt(0)" ::: "memory");
    }
    __builtin_amdgcn_sched_barrier(0);
    __builtin_amdgcn_s_barrier();          // tile t visible to all waves
    __builtin_amdgcn_sched_barrier(0);

    const unsigned short* Ac = As[t & 1];
    const unsigned short* Bc = Bs[t & 1];
    #pragma unroll
    for (int kk = 0; kk < 2; ++kk) {
      bf16x8 af[4], bfr[4];
      #pragma unroll
      for (int m = 0; m < 4; m++)
        af[m] = *reinterpret_cast<const bf16x8*>(
            &Ac[(m0w + m*16 + lr) * BKg + (((kk*4 + g) ^ (lr & 7)) << 3)]);
      #pragma unroll
      for (int n = 0; n < 4; n++)
        bfr[n] = *reinterpret_cast<const bf16x8*>(
            &Bc[(n0w + n*16 + lr) * BKg + (((kk*4 + g) ^ (lr & 7)) << 3)]);
      #pragma unroll
      for (int m = 0; m < 4; m++)
        #pragma unroll
        for (int n = 0; n < 4; n++)
          acc[m][n] = __builtin_amdgcn_mfma_f32_16x16x32_bf16(af[m], bfr[n], acc[m][n], 0, 0, 0);
    }
    __builtin_amdgcn_sched_barrier(0);
    __builtin_amdgcn_s_barrier();          // all waves done reading buf[t&1]
  }
#undef STAGE

  const int cr = g * 4;
  const int cc = lr;
  #pragma unroll
  for (int m = 0; m < 4; m++) {
    #pragma unroll
    for (int n = 0; n < 4; n++) {
      int row = bm + m0w + m*16 + cr;
      int col = bn + n0w + n*16 + cc;
      f32x4 a = acc[m][n];
      #pragma unroll
      for (int r = 0; r < 4; r++) {
        float v = a[r];
        if (bias)  v += bias[col];
        if (resid) v += resid[(size_t)(row + r) * ldc + col];
        if (relu)  v = fmaxf(v, 0.f);
        if (outF)  outF[(size_t)(row + r) * ldc + col] = v;
        if (outH)  outH[(size_t)(row + r) * ldc + col] = f2bf(v);
      }
    }
  }
}

// ---------------------------------------------------------------- MFMA flash attention (bf16 in/out)
__global__ __launch_bounds__(256) void attn_mfma(
    const unsigned short* __restrict__ qkv,  // bf16 [B*T][1536]
    unsigned short* __restrict__ o)          // bf16 [B*T][512]
{
  __shared__ __align__(16) unsigned short Ks[64*64];
  __shared__ __align__(16) unsigned short Vt[64*64];
  __shared__ __align__(16) unsigned short Ps[4][16*64];

  const int qb = (int)gridDim.x - 1 - (int)blockIdx.x;
  const int bh = blockIdx.y, bb = bh >> 3, hh = bh & 7;
  const int tid = threadIdx.x, lane = tid & 63, wv = tid >> 6;
  const int lr = lane & 15, g = lane >> 4;

  const unsigned short* qp = qkv + ((size_t)(bb*T_ + qb*64))*1536 + hh*64;
  const unsigned short* kp = qkv + ((size_t)bb*T_)*1536 + 512  + hh*64;
  const unsigned short* vp = qkv + ((size_t)bb*T_)*1536 + 1024 + hh*64;

  bf16x8 qf[2];
  qf[0] = *reinterpret_cast<const bf16x8*>(qp + (size_t)(wv*16 + lr)*1536 + g*8);
  qf[1] = *reinterpret_cast<const bf16x8*>(qp + (size_t)(wv*16 + lr)*1536 + 32 + g*8);

  f32x4 ov[4];
  #pragma unroll
  for (int n = 0; n < 4; n++) ov[n] = (f32x4){0.f, 0.f, 0.f, 0.f};
  float mrow[4] = {NEGBIG, NEGBIG, NEGBIG, NEGBIG};
  float lrow[4] = {0.f, 0.f, 0.f, 0.f};

  for (int s0 = 0; s0 <= qb; ++s0) {
    __syncthreads();
    #pragma unroll
    for (int i = 0; i < 2; i++) {
      int kv = i*32 + wv*8 + (lane >> 3);
      int hb = (lane & 7) ^ (lane >> 3);
      gl_lds16(kp + (size_t)(s0*64 + kv)*1536 + hb*8,
               (void*)(Ks + i*2048 + wv*512));
    }
    #pragma unroll
    for (int it = 0; it < 2; it++) {
      int c0 = wv*8 + it*32;
      union { uint4 v; unsigned short e[8]; } uv;
      uv.v = *reinterpret_cast<const uint4*>(vp + (size_t)(s0*64 + lane)*1536 + c0);
      #pragma unroll
      for (int j = 0; j < 8; j++)
        Vt[(c0 + j)*64 + (((lane >> 3) ^ j) << 3) + (lane & 7)] = uv.e[j];
    }
    __syncthreads();

    f32x4 sf[4];
    #pragma unroll
    for (int n = 0; n < 4; n++) sf[n] = (f32x4){0.f, 0.f, 0.f, 0.f};
    #pragma unroll
    for (int kk = 0; kk < 2; kk++) {
      #pragma unroll
      for (int n = 0; n < 4; n++) {
        const bf16x8 kf = *reinterpret_cast<const bf16x8*>(
            &Ks[(n*16 + lr)*64 + (((kk*4 + g) ^ (lr & 7)) << 3)]);
        sf[n] = __builtin_amdgcn_mfma_f32_16x16x32_bf16(qf[kk], kf, sf[n], 0, 0, 0);
      }
    }

    const int diag = (s0 == qb);
    float sv[4][4];
    #pragma unroll
    for (int n = 0; n < 4; n++)
      #pragma unroll
      for (int r = 0; r < 4; r++) {
        float xv = sf[n][r] * SCALE_;
        if (diag && (n*16 + lr) > (wv*16 + g*4 + r)) xv = NEGBIG;
        sv[n][r] = xv;
      }

    float aa[4];
    #pragma unroll
    for (int r = 0; r < 4; r++) {
      float pm = fmaxf(fmaxf(sv[0][r], sv[1][r]), fmaxf(sv[2][r], sv[3][r]));
      pm = fmaxf(pm, __shfl_xor(pm, 1));
      pm = fmaxf(pm, __shfl_xor(pm, 2));
      pm = fmaxf(pm, __shfl_xor(pm, 4));
      pm = fmaxf(pm, __shfl_xor(pm, 8));
      float mn = fmaxf(mrow[r], pm);
      aa[r] = __expf(mrow[r] - mn);
      mrow[r] = mn;
    }
    float rs[4] = {0.f, 0.f, 0.f, 0.f};
    #pragma unroll
    for (int n = 0; n < 4; n++)
      #pragma unroll
      for (int r = 0; r < 4; r++) {
        float p = __expf(sv[n][r] - mrow[r]);
        rs[r] += p;
        Ps[wv][(g*4 + r)*64 + ((((n << 1) + (lr >> 3)) ^ ((g*4 + r) & 7)) << 3) + (lr & 7)] = f2bf(p);
      }
    #pragma unroll
    for (int r = 0; r < 4; r++) {
      float s = rs[r];
      s += __shfl_xor(s, 1); s += __shfl_xor(s, 2);
      s += __shfl_xor(s, 4); s += __shfl_xor(s, 8);
      lrow[r] = lrow[r]*aa[r] + s;
    }
    #pragma unroll
    for (int n = 0; n < 4; n++)
      #pragma unroll
      for (int r = 0; r < 4; r++)
        ov[n][r] *= aa[r];

    #pragma unroll
    for (int kk = 0; kk < 2; kk++) {
      const bf16x8 pf = *reinterpret_cast<const bf16x8*>(
          &Ps[wv][lr*64 + (((kk*4 + g) ^ (lr & 7)) << 3)]);
      #pragma unroll
      for (int n = 0; n < 4; n++) {
        const bf16x8 vf = *reinterpret_cast<const bf16x8*>(
            &Vt[(n*16 + lr)*64 + (((kk*4 + g) ^ (lr & 7)) << 3)]);
        ov[n] = __builtin_amdgcn_mfma_f32_16x16x32_bf16(pf, vf, ov[n], 0, 0, 0);
      }
    }
  }

  #pragma unroll
  for (int r = 0; r < 4; r++) {
    float inv = 1.0f / lrow[r];
    size_t row = (size_t)(bb*T_ + qb*64 + wv*16 + g*4 + r);
    #pragma unroll
    for (int n = 0; n < 4; n++)
      o[row*D_ + hh*64 + n*16 + lr] = f2bf(ov[n][r] * inv);
  }
}

// ---------------------------------------------------------------- loss (one-pass online softmax)
__global__ __launch_bounds__(256) void loss_row_kernel(
    const float* __restrict__ logits, const int* __restrict__ labels,
    float* __restrict__ rowloss)
{
  __shared__ float redm[4], reds[4];
  const int row = blockIdx.x;
  const float* lr = logits + (size_t)row * V_;
  const float4* l4 = reinterpret_cast<const float4*>(lr);
  const int tid = threadIdx.x, lane = tid & 63, wid = tid >> 6;
  float m = -INFINITY, s = 0.f;
  for (int c = tid; c < V_/4; c += 256) {
    float4 v = l4[c];
    float bm = fmaxf(fmaxf(v.x, v.y), fmaxf(v.z, v.w));
    if (bm > m) { s *= __expf(m - bm); m = bm; }
    s += __expf(v.x - m) + __expf(v.y - m) + __expf(v.z - m) + __expf(v.w - m);
  }
  #pragma unroll
  for (int off = 1; off < 64; off <<= 1) {
    float mo = __shfl_xor(m, off), so = __shfl_xor(s, off);
    float mn = fmaxf(m, mo);
    s = s * __expf(m - mn) + so * __expf(mo - mn);
    m = mn;
  }
  if (lane == 0) { redm[wid] = m; reds[wid] = s; }
  __syncthreads();
  if (tid == 0) {
    float M = redm[0], S = reds[0];
    #pragma unroll
    for (int w = 1; w < 4; w++) {
      float mn = fmaxf(M, redm[w]);
      S = S * __expf(M - mn) + reds[w] * __expf(redm[w] - mn);
      M = mn;
    }
    rowloss[row] = lr[labels[row]] - M - logf(S);
  }
}

__global__ __launch_bounds__(256) void loss_final_kernel(
    const float* __restrict__ rowloss, float* __restrict__ out)
{
  __shared__ float red[4];
  const int tid = threadIdx.x, lane = tid & 63, wid = tid >> 6;
  float s = 0.f;
  for (int i = tid; i < BT_; i += 256) s += rowloss[i];
  #pragma unroll
  for (int off = 1; off < 64; off <<= 1) s += __shfl_xor(s, off);
  if (lane == 0) red[wid] = s;
  __syncthreads();
  if (tid == 0) out[0] = -(red[0] + red[1] + red[2] + red[3]) * (1.0f / BT_);
}

// ---------------------------------------------------------------- launch
extern "C" void kernel_launch(void* const* d_in, const int* in_sizes, int n_in,
                              void* d_out, int out_size, void* d_ws, size_t ws_size,
                              hipStream_t stream)
{
  (void)in_sizes; (void)n_in; (void)out_size; (void)ws_size;
  const int*   ids    = (const int*)d_in[0];
  const int*   labels = (const int*)d_in[1];
  const float* tok    = (const float*)d_in[2];
  const float* pos    = (const float*)d_in[3];
  const float* Wq     = (const float*)d_in[4];
  const float* Wk     = (const float*)d_in[5];
  const float* Wv     = (const float*)d_in[6];
  const float* Wo     = (const float*)d_in[7];
  const float* bo     = (const float*)d_in[8];
  const float* ln1g   = (const float*)d_in[9];
  const float* ln1b   = (const float*)d_in[10];
  const float* ln2g   = (const float*)d_in[11];
  const float* ln2b   = (const float*)d_in[12];
  const float* W1     = (const float*)d_in[13];
  const float* b1     = (const float*)d_in[14];
  const float* W2     = (const float*)d_in[15];
  const float* b2     = (const float*)d_in[16];
  const float* lnfg   = (const float*)d_in[17];
  const float* lnfb   = (const float*)d_in[18];
  const float* Wp     = (const float*)d_in[19];
  const float* bp     = (const float*)d_in[20];

  float* out = (float*)d_out;
  char* base = (char*)d_ws;
  float*          x       = (float*)(base + 0);                 //  8,388,608
  unsigned short* xn      = (unsigned short*)(base + 8388608);  //  4,194,304
  float*          rowloss = (float*)(base + 12582912);          //     16,384
  unsigned short* WqkvT   = (unsigned short*)(base + 12599296); //  6,291,456
  unsigned short* W1T     = (unsigned short*)(base + 18890752); //  8,388,608
  unsigned short* W2T     = (unsigned short*)(base + 27279360); //  8,388,608
  unsigned short* WoT     = (unsigned short*)(base + 35667968); //  2,097,152
  unsigned short* qkvh    = (unsigned short*)(base + 37765120); // 12,582,912
  unsigned short* ob      = (unsigned short*)(base + 50348032); //  4,194,304
  unsigned short* h1      = (unsigned short*)(base + 54542336); // 16,777,216
  unsigned short* WpT     = (unsigned short*)(base + 37765120); // 32,768,000 (alias: dead at logits time)

  embed_kernel<<<BT_ * D_ / 4 / 256, 256, 0, stream>>>(ids, tok, pos, x);

  qkvw_transpose<<<dim3(16, 2, 96), 256, 0, stream>>>(Wq, Wk, Wv, WqkvT);
  transpose_cast<<<dim3(16, 64, 4), 256, 0, stream>>>(W1, W1T, 2048, 512, 1048576, 1048576);
  transpose_cast<<<dim3(64, 16, 4), 256, 0, stream>>>(W2, W2T, 512, 2048, 1048576, 1048576);
  transpose_cast<<<dim3(16, 16, 4), 256, 0, stream>>>(Wo, WoT, 512, 512, 262144, 262144);

  for (int l = 0; l < NL_; l++) {
    ln_kernel<<<BT_ / 4, 256, 0, stream>>>(x, ln1g + l * D_, ln1b + l * D_, xn);
    gemm_mfma<<<dim3(BT_ / BM, 1536 / BN), 256, 0, stream>>>(
        xn, WqkvT + (size_t)l * 1536 * 512, 512, nullptr, nullptr, nullptr, qkvh, 1536, 0);
    attn_mfma<<<dim3(T_ / 64, B_ * H_), 256, 0, stream>>>(qkvh, ob);
    gemm_mfma<<<dim3(BT_ / BM, D_ / BN), 256, 0, stream>>>(
        ob, WoT + (size_t)l * 512 * 512, 512, bo + l * D_, x, x, nullptr, D_, 0);
    ln_kernel<<<BT_ / 4, 256, 0, stream>>>(x, ln2g + l * D_, ln2b + l * D_, xn);
    gemm_mfma<<<dim3(BT_ / BM, 4 * D_ / BN), 256, 0, stream>>>(
        xn, W1T + (size_t)l * 2048 * 512, 512, b1 + l * 4 * D_, nullptr, nullptr, h1, 4 * D_, 1);
    gemm_mfma<<<dim3(BT_ / BM, D_ / BN), 256, 0, stream>>>(
        h1, W2T + (size_t)l * 512 * 2048, 2048, b2 + l * D_, x, x, nullptr, D_, 0);
  }

  transpose_cast<<<dim3(16, 1000, 1), 256, 0, stream>>>(Wp, WpT, 32000, 512, 0, 0);
  ln_kernel<<<BT_ / 4, 256, 0, stream>>>(x, lnfg, lnfb, xn);
  gemm_mfma<<<dim3(BT_ / BM, V_ / BN), 256, 0, stream>>>(
      xn, WpT, 512, bp, nullptr, out, nullptr, V_, 0);

  loss_row_kernel<<<BT_, 256, 0, stream>>>(out, labels, rowloss);
  loss_final_kernel<<<1, 256, 0, stream>>>(rowloss, out + (size_t)BT_ * V_);
}

// Round 5
// 1436.657 us; speedup vs baseline: 3.3548x; 1.0594x over previous
//
#include <hip/hip_runtime.h>
#include <hip/hip_bf16.h>
#include <math.h>

#define B_ 2
#define T_ 2048
#define D_ 512
#define H_ 8
#define NL_ 4
#define V_ 32000
#define HD_ 64
#define BT_ (B_*T_)
#define EPS_ 1e-5f
#define SCALE_ 0.04419417382415922f  /* 1/sqrt(512) — source scales by D, not HD */
#define NEGBIG -1e30f

typedef __bf16 bf16x8 __attribute__((ext_vector_type(8)));
typedef float  f32x4  __attribute__((ext_vector_type(4)));

__device__ __forceinline__ unsigned short f2bf(float f) {
  union { float f; unsigned u; } v; v.f = f;
  unsigned r = v.u + 0x7fff + ((v.u >> 16) & 1);
  return (unsigned short)(r >> 16);
}

__device__ __forceinline__ void gl_lds16(const void* g, void* l) {
  __builtin_amdgcn_global_load_lds(
      (const __attribute__((address_space(1))) void*)g,
      (__attribute__((address_space(3))) void*)l, 16, 0, 0);
}

// ---------------------------------------------------------------- embed
__global__ __launch_bounds__(256) void embed_kernel(
    const int* __restrict__ ids, const float* __restrict__ tok,
    const float* __restrict__ pos, float* __restrict__ x)
{
  int i = blockIdx.x * 256 + threadIdx.x;
  int d4 = i & (D_/4 - 1);
  int bt = i >> 7;
  int t  = bt & (T_ - 1);
  const float4 a = reinterpret_cast<const float4*>(tok + (size_t)ids[bt] * D_)[d4];
  const float4 p = reinterpret_cast<const float4*>(pos + (size_t)t * D_)[d4];
  float4 r; r.x = a.x + p.x; r.y = a.y + p.y; r.z = a.z + p.z; r.w = a.w + p.w;
  reinterpret_cast<float4*>(x)[i] = r;
}

// ---------------------------------------------------------------- layernorm -> bf16 out
__global__ __launch_bounds__(256) void ln_kernel(
    const float* __restrict__ x, const float* __restrict__ g,
    const float* __restrict__ b, unsigned short* __restrict__ out)
{
  int row  = blockIdx.x * 4 + (threadIdx.x >> 6);
  int lane = threadIdx.x & 63;
  const float4* xr = reinterpret_cast<const float4*>(x + (size_t)row * D_);
  float4 v0 = xr[lane], v1 = xr[lane + 64];
  float s = v0.x + v0.y + v0.z + v0.w + v1.x + v1.y + v1.z + v1.w;
  float q = v0.x*v0.x + v0.y*v0.y + v0.z*v0.z + v0.w*v0.w
          + v1.x*v1.x + v1.y*v1.y + v1.z*v1.z + v1.w*v1.w;
  #pragma unroll
  for (int off = 1; off < 64; off <<= 1) {
    s += __shfl_xor(s, off);
    q += __shfl_xor(q, off);
  }
  float mean = s * (1.0f / D_);
  float var  = q * (1.0f / D_) - mean * mean;
  float rs   = rsqrtf(var + EPS_);
  const float4* g4 = reinterpret_cast<const float4*>(g);
  const float4* b4 = reinterpret_cast<const float4*>(b);
  float4 gv0 = g4[lane], gv1 = g4[lane + 64];
  float4 bv0 = b4[lane], bv1 = b4[lane + 64];
  ushort4 p0, p1;
  p0.x = f2bf((v0.x - mean) * rs * gv0.x + bv0.x);
  p0.y = f2bf((v0.y - mean) * rs * gv0.y + bv0.y);
  p0.z = f2bf((v0.z - mean) * rs * gv0.z + bv0.z);
  p0.w = f2bf((v0.w - mean) * rs * gv0.w + bv0.w);
  p1.x = f2bf((v1.x - mean) * rs * gv1.x + bv1.x);
  p1.y = f2bf((v1.y - mean) * rs * gv1.y + bv1.y);
  p1.z = f2bf((v1.z - mean) * rs * gv1.z + bv1.z);
  p1.w = f2bf((v1.w - mean) * rs * gv1.w + bv1.w);
  unsigned short* orow = out + (size_t)row * D_;
  *reinterpret_cast<ushort4*>(orow + lane * 4)       = p0;
  *reinterpret_cast<ushort4*>(orow + 256 + lane * 4) = p1;
}

// ---------------------------------------------------------------- transpose+cast fp32 [R][C] -> bf16 [C][R]
__global__ __launch_bounds__(256) void transpose_cast(
    const float* __restrict__ src, unsigned short* __restrict__ dst,
    int C, int R, long sstride, long dstride)
{
  src += (size_t)blockIdx.z * sstride;
  dst += (size_t)blockIdx.z * dstride;
  __shared__ float t[32][33];
  int r0 = blockIdx.x * 32, c0 = blockIdx.y * 32;
  int tx = threadIdx.x & 31, ty = threadIdx.x >> 5;
  #pragma unroll
  for (int i = 0; i < 4; i++)
    t[ty + i*8][tx] = src[(size_t)(r0 + ty + i*8) * C + c0 + tx];
  __syncthreads();
  #pragma unroll
  for (int i = 0; i < 4; i++)
    dst[(size_t)(c0 + ty + i*8) * R + r0 + tx] = f2bf(t[tx][ty + i*8]);
}

// WqkvT[l][mat*512 + h*64 + e][d] = W{q,k,v}[l][h][d][e]
__global__ __launch_bounds__(256) void qkvw_transpose(
    const float* __restrict__ Wq, const float* __restrict__ Wk,
    const float* __restrict__ Wv, unsigned short* __restrict__ dst)
{
  int z = blockIdx.z; int l = z / 24; int rem = z % 24; int mat = rem >> 3; int h = rem & 7;
  const float* W = (mat == 0 ? Wq : (mat == 1 ? Wk : Wv)) + ((size_t)(l * 8 + h)) * D_ * HD_;
  unsigned short* d = dst + ((size_t)l * 1536 + mat * 512 + h * 64) * D_;
  __shared__ float t[32][33];
  int d0 = blockIdx.x * 32, e0 = blockIdx.y * 32;
  int tx = threadIdx.x & 31, ty = threadIdx.x >> 5;
  #pragma unroll
  for (int i = 0; i < 4; i++)
    t[ty + i*8][tx] = W[(size_t)(d0 + ty + i*8) * HD_ + e0 + tx];
  __syncthreads();
  #pragma unroll
  for (int i = 0; i < 4; i++)
    d[(size_t)(e0 + ty + i*8) * D_ + d0 + tx] = f2bf(t[tx][ty + i*8]);
}

// ---------------------------------------------------------------- pipelined bf16 MFMA GEMM
// BM=128 x BN_T tile, BK=32, 4 LDS buffers, prefetch depth 3, counted vmcnt.
// LDS chunk swizzle: row r, 16B-chunk slot s holds global chunk s ^ ((r>>1)&3);
// realized on the write side by pre-swizzling the global source (gl_lds dest
// stays linear), on the read side by slot = g ^ ((lr>>1)&3). 2-way max alias.
#define WAITVM(n) asm volatile("s_waitcnt vmcnt(" #n ")" ::: "memory")

template<int BN_T, int WM, int WN>
__global__ __launch_bounds__(256) void gemm_pipe(
    const unsigned short* __restrict__ A,
    const unsigned short* __restrict__ Bt,
    int K,
    const float* __restrict__ bias,
    const float* __restrict__ resid,
    float* __restrict__ outF,
    unsigned short* __restrict__ outH,
    int ldc, int relu)
{
  constexpr int BKp = 32;
  constexpr int ALOADS = 2;              // 128 rows / (4 waves * 16 rows/load)
  constexpr int BLOADS = BN_T / 64;      // 2 (BN=128) or 1 (BN=64)
  constexpr int LOADS  = ALOADS + BLOADS;
  constexpr int MR = 128 / (16 * WM);
  constexpr int NR = BN_T / (16 * WN);
  __shared__ __align__(16) unsigned short As[4][128 * BKp];
  __shared__ __align__(16) unsigned short Bs[4][BN_T * BKp];

  const int tid = threadIdx.x;
  const int lane = tid & 63, wv = tid >> 6;
  const int lr = lane & 15, g = lane >> 4;

  // XCD-aware bijective block swizzle (all grids here have nwg%8==0)
  const int gx = gridDim.x;
  int id = blockIdx.y * gx + blockIdx.x;
  const int nwg = gx * gridDim.y;
  if ((nwg & 7) == 0) {
    const int q = nwg >> 3;
    id = (id & 7) * q + (id >> 3);
  }
  const int bm = (id % gx) * 128, bn = (id / gx) * BN_T;

  const int m0w = (wv / WN) * (128 / WM);
  const int n0w = (wv % WN) * (BN_T / WN);

  // staging: lane covers row base + (lane>>2), slot lane&3 gets global chunk schk
  const int schk = (lane & 3) ^ ((lane >> 3) & 3);
  const unsigned short* Ab = A  + (size_t)(bm + wv*32 + (lane >> 2)) * K + schk * 8;
  const unsigned short* Bb = Bt + (size_t)(bn + wv*(BN_T/4) + (lane >> 2)) * K + schk * 8;

#define STAGEP(s)                                                               \
  { const int kof_ = (s) * BKp; unsigned short* Ad_ = As[(s) & 3] + wv*1024;    \
    unsigned short* Bd_ = Bs[(s) & 3] + wv*(BLOADS*512);                        \
    _Pragma("unroll")                                                           \
    for (int i_ = 0; i_ < ALOADS; ++i_)                                         \
      gl_lds16(Ab + (size_t)(i_*16)*K + kof_, Ad_ + i_*512);                    \
    _Pragma("unroll")                                                           \
    for (int i_ = 0; i_ < BLOADS; ++i_)                                         \
      gl_lds16(Bb + (size_t)(i_*16)*K + kof_, Bd_ + i_*512); }

  f32x4 acc[MR][NR];
  #pragma unroll
  for (int m = 0; m < MR; m++)
    #pragma unroll
    for (int n = 0; n < NR; n++)
      acc[m][n] = (f32x4){0.f, 0.f, 0.f, 0.f};

  const int nt = K >> 5;                  // >= 16 for all K here
  STAGEP(0); STAGEP(1); STAGEP(2);

  const int slotx = (g ^ ((lr >> 1) & 3)) << 3;  // read-side swizzled chunk (elems)

  for (int t = 0; t < nt; ++t) {
    const int s = t + 3;
    __builtin_amdgcn_sched_barrier(0);
    if (s < nt) {
      STAGEP(s);
      if constexpr (LOADS == 4) WAITVM(12); else WAITVM(9);
    } else if (s == nt) {
      if constexpr (LOADS == 4) WAITVM(8); else WAITVM(6);
    } else if (s == nt + 1) {
      if constexpr (LOADS == 4) WAITVM(4); else WAITVM(3);
    } else {
      WAITVM(0);
    }
    __builtin_amdgcn_sched_barrier(0);
    __builtin_amdgcn_s_barrier();         // tile t visible to all waves
    __builtin_amdgcn_sched_barrier(0);

    const unsigned short* Ac = As[t & 3];
    const unsigned short* Bc = Bs[t & 3];
    bf16x8 af[MR], bfr[NR];
    #pragma unroll
    for (int m = 0; m < MR; m++)
      af[m] = *reinterpret_cast<const bf16x8*>(&Ac[(m0w + m*16 + lr) * BKp + slotx]);
    #pragma unroll
    for (int n = 0; n < NR; n++)
      bfr[n] = *reinterpret_cast<const bf16x8*>(&Bc[(n0w + n*16 + lr) * BKp + slotx]);
    #pragma unroll
    for (int m = 0; m < MR; m++)
      #pragma unroll
      for (int n = 0; n < NR; n++)
        acc[m][n] = __builtin_amdgcn_mfma_f32_16x16x32_bf16(af[m], bfr[n], acc[m][n], 0, 0, 0);

    __builtin_amdgcn_sched_barrier(0);
    __builtin_amdgcn_s_barrier();         // all waves done reading buf[t&3]
  }
#undef STAGEP

  const int cr = g * 4;
  const int cc = lr;
  #pragma unroll
  for (int m = 0; m < MR; m++) {
    #pragma unroll
    for (int n = 0; n < NR; n++) {
      int row = bm + m0w + m*16 + cr;
      int col = bn + n0w + n*16 + cc;
      f32x4 a = acc[m][n];
      #pragma unroll
      for (int r = 0; r < 4; r++) {
        float v = a[r];
        if (bias)  v += bias[col];
        if (resid) v += resid[(size_t)(row + r) * ldc + col];
        if (relu)  v = fmaxf(v, 0.f);
        if (outF)  outF[(size_t)(row + r) * ldc + col] = v;
        if (outH)  outH[(size_t)(row + r) * ldc + col] = f2bf(v);
      }
    }
  }
}

// ---------------------------------------------------------------- MFMA flash attention (bf16 in/out)
__global__ __launch_bounds__(256) void attn_mfma(
    const unsigned short* __restrict__ qkv,  // bf16 [B*T][1536]
    unsigned short* __restrict__ o)          // bf16 [B*T][512]
{
  __shared__ __align__(16) unsigned short Ks[64*64];
  __shared__ __align__(16) unsigned short Vt[64*64];
  __shared__ __align__(16) unsigned short Ps[4][16*64];

  const int qb = (int)gridDim.x - 1 - (int)blockIdx.x;
  const int bh = blockIdx.y, bb = bh >> 3, hh = bh & 7;
  const int tid = threadIdx.x, lane = tid & 63, wv = tid >> 6;
  const int lr = lane & 15, g = lane >> 4;

  const unsigned short* qp = qkv + ((size_t)(bb*T_ + qb*64))*1536 + hh*64;
  const unsigned short* kp = qkv + ((size_t)bb*T_)*1536 + 512  + hh*64;
  const unsigned short* vp = qkv + ((size_t)bb*T_)*1536 + 1024 + hh*64;

  bf16x8 qf[2];
  qf[0] = *reinterpret_cast<const bf16x8*>(qp + (size_t)(wv*16 + lr)*1536 + g*8);
  qf[1] = *reinterpret_cast<const bf16x8*>(qp + (size_t)(wv*16 + lr)*1536 + 32 + g*8);

  f32x4 ov[4];
  #pragma unroll
  for (int n = 0; n < 4; n++) ov[n] = (f32x4){0.f, 0.f, 0.f, 0.f};
  float mrow[4] = {NEGBIG, NEGBIG, NEGBIG, NEGBIG};
  float lrow[4] = {0.f, 0.f, 0.f, 0.f};

  for (int s0 = 0; s0 <= qb; ++s0) {
    __syncthreads();
    #pragma unroll
    for (int i = 0; i < 2; i++) {
      int kv = i*32 + wv*8 + (lane >> 3);
      int hb = (lane & 7) ^ (lane >> 3);
      gl_lds16(kp + (size_t)(s0*64 + kv)*1536 + hb*8,
               (void*)(Ks + i*2048 + wv*512));
    }
    #pragma unroll
    for (int it = 0; it < 2; it++) {
      int c0 = wv*8 + it*32;
      union { uint4 v; unsigned short e[8]; } uv;
      uv.v = *reinterpret_cast<const uint4*>(vp + (size_t)(s0*64 + lane)*1536 + c0);
      #pragma unroll
      for (int j = 0; j < 8; j++)
        Vt[(c0 + j)*64 + (((lane >> 3) ^ j) << 3) + (lane & 7)] = uv.e[j];
    }
    __syncthreads();

    f32x4 sf[4];
    #pragma unroll
    for (int n = 0; n < 4; n++) sf[n] = (f32x4){0.f, 0.f, 0.f, 0.f};
    #pragma unroll
    for (int kk = 0; kk < 2; kk++) {
      #pragma unroll
      for (int n = 0; n < 4; n++) {
        const bf16x8 kf = *reinterpret_cast<const bf16x8*>(
            &Ks[(n*16 + lr)*64 + (((kk*4 + g) ^ (lr & 7)) << 3)]);
        sf[n] = __builtin_amdgcn_mfma_f32_16x16x32_bf16(qf[kk], kf, sf[n], 0, 0, 0);
      }
    }

    const int diag = (s0 == qb);
    float sv[4][4];
    #pragma unroll
    for (int n = 0; n < 4; n++)
      #pragma unroll
      for (int r = 0; r < 4; r++) {
        float xv = sf[n][r] * SCALE_;
        if (diag && (n*16 + lr) > (wv*16 + g*4 + r)) xv = NEGBIG;
        sv[n][r] = xv;
      }

    float aa[4];
    #pragma unroll
    for (int r = 0; r < 4; r++) {
      float pm = fmaxf(fmaxf(sv[0][r], sv[1][r]), fmaxf(sv[2][r], sv[3][r]));
      pm = fmaxf(pm, __shfl_xor(pm, 1));
      pm = fmaxf(pm, __shfl_xor(pm, 2));
      pm = fmaxf(pm, __shfl_xor(pm, 4));
      pm = fmaxf(pm, __shfl_xor(pm, 8));
      float mn = fmaxf(mrow[r], pm);
      aa[r] = __expf(mrow[r] - mn);
      mrow[r] = mn;
    }
    float rs[4] = {0.f, 0.f, 0.f, 0.f};
    #pragma unroll
    for (int n = 0; n < 4; n++)
      #pragma unroll
      for (int r = 0; r < 4; r++) {
        float p = __expf(sv[n][r] - mrow[r]);
        rs[r] += p;
        Ps[wv][(g*4 + r)*64 + ((((n << 1) + (lr >> 3)) ^ ((g*4 + r) & 7)) << 3) + (lr & 7)] = f2bf(p);
      }
    #pragma unroll
    for (int r = 0; r < 4; r++) {
      float s = rs[r];
      s += __shfl_xor(s, 1); s += __shfl_xor(s, 2);
      s += __shfl_xor(s, 4); s += __shfl_xor(s, 8);
      lrow[r] = lrow[r]*aa[r] + s;
    }
    #pragma unroll
    for (int n = 0; n < 4; n++)
      #pragma unroll
      for (int r = 0; r < 4; r++)
        ov[n][r] *= aa[r];

    #pragma unroll
    for (int kk = 0; kk < 2; kk++) {
      const bf16x8 pf = *reinterpret_cast<const bf16x8*>(
          &Ps[wv][lr*64 + (((kk*4 + g) ^ (lr & 7)) << 3)]);
      #pragma unroll
      for (int n = 0; n < 4; n++) {
        const bf16x8 vf = *reinterpret_cast<const bf16x8*>(
            &Vt[(n*16 + lr)*64 + (((kk*4 + g) ^ (lr & 7)) << 3)]);
        ov[n] = __builtin_amdgcn_mfma_f32_16x16x32_bf16(pf, vf, ov[n], 0, 0, 0);
      }
    }
  }

  #pragma unroll
  for (int r = 0; r < 4; r++) {
    float inv = 1.0f / lrow[r];
    size_t row = (size_t)(bb*T_ + qb*64 + wv*16 + g*4 + r);
    #pragma unroll
    for (int n = 0; n < 4; n++)
      o[row*D_ + hh*64 + n*16 + lr] = f2bf(ov[n][r] * inv);
  }
}

// ---------------------------------------------------------------- loss (one-pass online softmax)
__global__ __launch_bounds__(256) void loss_row_kernel(
    const float* __restrict__ logits, const int* __restrict__ labels,
    float* __restrict__ rowloss)
{
  __shared__ float redm[4], reds[4];
  const int row = blockIdx.x;
  const float* lr = logits + (size_t)row * V_;
  const float4* l4 = reinterpret_cast<const float4*>(lr);
  const int tid = threadIdx.x, lane = tid & 63, wid = tid >> 6;
  float m = -INFINITY, s = 0.f;
  for (int c = tid; c < V_/4; c += 256) {
    float4 v = l4[c];
    float bm = fmaxf(fmaxf(v.x, v.y), fmaxf(v.z, v.w));
    if (bm > m) { s *= __expf(m - bm); m = bm; }
    s += __expf(v.x - m) + __expf(v.y - m) + __expf(v.z - m) + __expf(v.w - m);
  }
  #pragma unroll
  for (int off = 1; off < 64; off <<= 1) {
    float mo = __shfl_xor(m, off), so = __shfl_xor(s, off);
    float mn = fmaxf(m, mo);
    s = s * __expf(m - mn) + so * __expf(mo - mn);
    m = mn;
  }
  if (lane == 0) { redm[wid] = m; reds[wid] = s; }
  __syncthreads();
  if (tid == 0) {
    float M = redm[0], S = reds[0];
    #pragma unroll
    for (int w = 1; w < 4; w++) {
      float mn = fmaxf(M, redm[w]);
      S = S * __expf(M - mn) + reds[w] * __expf(redm[w] - mn);
      M = mn;
    }
    rowloss[row] = lr[labels[row]] - M - logf(S);
  }
}

__global__ __launch_bounds__(256) void loss_final_kernel(
    const float* __restrict__ rowloss, float* __restrict__ out)
{
  __shared__ float red[4];
  const int tid = threadIdx.x, lane = tid & 63, wid = tid >> 6;
  float s = 0.f;
  for (int i = tid; i < BT_; i += 256) s += rowloss[i];
  #pragma unroll
  for (int off = 1; off < 64; off <<= 1) s += __shfl_xor(s, off);
  if (lane == 0) red[wid] = s;
  __syncthreads();
  if (tid == 0) out[0] = -(red[0] + red[1] + red[2] + red[3]) * (1.0f / BT_);
}

// ---------------------------------------------------------------- launch
extern "C" void kernel_launch(void* const* d_in, const int* in_sizes, int n_in,
                              void* d_out, int out_size, void* d_ws, size_t ws_size,
                              hipStream_t stream)
{
  (void)in_sizes; (void)n_in; (void)out_size; (void)ws_size;
  const int*   ids    = (const int*)d_in[0];
  const int*   labels = (const int*)d_in[1];
  const float* tok    = (const float*)d_in[2];
  const float* pos    = (const float*)d_in[3];
  const float* Wq     = (const float*)d_in[4];
  const float* Wk     = (const float*)d_in[5];
  const float* Wv     = (const float*)d_in[6];
  const float* Wo     = (const float*)d_in[7];
  const float* bo     = (const float*)d_in[8];
  const float* ln1g   = (const float*)d_in[9];
  const float* ln1b   = (const float*)d_in[10];
  const float* ln2g   = (const float*)d_in[11];
  const float* ln2b   = (const float*)d_in[12];
  const float* W1     = (const float*)d_in[13];
  const float* b1     = (const float*)d_in[14];
  const float* W2     = (const float*)d_in[15];
  const float* b2     = (const float*)d_in[16];
  const float* lnfg   = (const float*)d_in[17];
  const float* lnfb   = (const float*)d_in[18];
  const float* Wp     = (const float*)d_in[19];
  const float* bp     = (const float*)d_in[20];

  float* out = (float*)d_out;
  char* base = (char*)d_ws;
  float*          x       = (float*)(base + 0);                 //  8,388,608
  unsigned short* xn      = (unsigned short*)(base + 8388608);  //  4,194,304
  float*          rowloss = (float*)(base + 12582912);          //     16,384
  unsigned short* WqkvT   = (unsigned short*)(base + 12599296); //  6,291,456
  unsigned short* W1T     = (unsigned short*)(base + 18890752); //  8,388,608
  unsigned short* W2T     = (unsigned short*)(base + 27279360); //  8,388,608
  unsigned short* WoT     = (unsigned short*)(base + 35667968); //  2,097,152
  unsigned short* qkvh    = (unsigned short*)(base + 37765120); // 12,582,912
  unsigned short* ob      = (unsigned short*)(base + 50348032); //  4,194,304
  unsigned short* h1      = (unsigned short*)(base + 54542336); // 16,777,216
  unsigned short* WpT     = (unsigned short*)(base + 37765120); // 32,768,000 (alias: dead at logits time)

  embed_kernel<<<BT_ * D_ / 4 / 256, 256, 0, stream>>>(ids, tok, pos, x);

  qkvw_transpose<<<dim3(16, 2, 96), 256, 0, stream>>>(Wq, Wk, Wv, WqkvT);
  transpose_cast<<<dim3(16, 64, 4), 256, 0, stream>>>(W1, W1T, 2048, 512, 1048576, 1048576);
  transpose_cast<<<dim3(64, 16, 4), 256, 0, stream>>>(W2, W2T, 512, 2048, 1048576, 1048576);
  transpose_cast<<<dim3(16, 16, 4), 256, 0, stream>>>(Wo, WoT, 512, 512, 262144, 262144);

  for (int l = 0; l < NL_; l++) {
    ln_kernel<<<BT_ / 4, 256, 0, stream>>>(x, ln1g + l * D_, ln1b + l * D_, xn);
    gemm_pipe<128,2,2><<<dim3(32, 12), 256, 0, stream>>>(
        xn, WqkvT + (size_t)l * 1536 * 512, 512, nullptr, nullptr, nullptr, qkvh, 1536, 0);
    attn_mfma<<<dim3(T_ / 64, B_ * H_), 256, 0, stream>>>(qkvh, ob);
    gemm_pipe<64,4,1><<<dim3(32, 8), 256, 0, stream>>>(
        ob, WoT + (size_t)l * 512 * 512, 512, bo + l * D_, x, x, nullptr, D_, 0);
    ln_kernel<<<BT_ / 4, 256, 0, stream>>>(x, ln2g + l * D_, ln2b + l * D_, xn);
    gemm_pipe<128,2,2><<<dim3(32, 16), 256, 0, stream>>>(
        xn, W1T + (size_t)l * 2048 * 512, 512, b1 + l * 4 * D_, nullptr, nullptr, h1, 4 * D_, 1);
    gemm_pipe<64,4,1><<<dim3(32, 8), 256, 0, stream>>>(
        h1, W2T + (size_t)l * 512 * 2048, 2048, b2 + l * D_, x, x, nullptr, D_, 0);
  }

  transpose_cast<<<dim3(16, 1000, 1), 256, 0, stream>>>(Wp, WpT, 32000, 512, 0, 0);
  ln_kernel<<<BT_ / 4, 256, 0, stream>>>(x, lnfg, lnfb, xn);
  gemm_pipe<128,2,2><<<dim3(32, 250), 256, 0, stream>>>(
      xn, WpT, 512, bp, nullptr, out, nullptr, V_, 0);

  loss_row_kernel<<<BT_, 256, 0, stream>>>(out, labels, rowloss);
  loss_final_kernel<<<1, 256, 0, stream>>>(rowloss, out + (size_t)BT_ * V_);
}

// Round 6
// 1253.962 us; speedup vs baseline: 3.8436x; 1.1457x over previous
//
#include <hip/hip_runtime.h>
#include <hip/hip_bf16.h>
#include <math.h>

#define B_ 2
#define T_ 2048
#define D_ 512
#define H_ 8
#define NL_ 4
#define V_ 32000
#define HD_ 64
#define BT_ (B_*T_)
#define EPS_ 1e-5f
#define SCALE_ 0.04419417382415922f  /* 1/sqrt(512) — source scales by D, not HD */
#define NEGBIG -1e30f

typedef __bf16 bf16x8 __attribute__((ext_vector_type(8)));
typedef float  f32x4  __attribute__((ext_vector_type(4)));

__device__ __forceinline__ unsigned short f2bf(float f) {
  union { float f; unsigned u; } v; v.f = f;
  unsigned r = v.u + 0x7fff + ((v.u >> 16) & 1);
  return (unsigned short)(r >> 16);
}

__device__ __forceinline__ void gl_lds16(const void* g, void* l) {
  __builtin_amdgcn_global_load_lds(
      (const __attribute__((address_space(1))) void*)g,
      (__attribute__((address_space(3))) void*)l, 16, 0, 0);
}

#define WAITVM(n) asm volatile("s_waitcnt vmcnt(" #n ")" ::: "memory")

// ---------------------------------------------------------------- embed
__global__ __launch_bounds__(256) void embed_kernel(
    const int* __restrict__ ids, const float* __restrict__ tok,
    const float* __restrict__ pos, float* __restrict__ x)
{
  int i = blockIdx.x * 256 + threadIdx.x;
  int d4 = i & (D_/4 - 1);
  int bt = i >> 7;
  int t  = bt & (T_ - 1);
  const float4 a = reinterpret_cast<const float4*>(tok + (size_t)ids[bt] * D_)[d4];
  const float4 p = reinterpret_cast<const float4*>(pos + (size_t)t * D_)[d4];
  float4 r; r.x = a.x + p.x; r.y = a.y + p.y; r.z = a.z + p.z; r.w = a.w + p.w;
  reinterpret_cast<float4*>(x)[i] = r;
}

// ---------------------------------------------------------------- layernorm -> bf16 out
__global__ __launch_bounds__(256) void ln_kernel(
    const float* __restrict__ x, const float* __restrict__ g,
    const float* __restrict__ b, unsigned short* __restrict__ out)
{
  int row  = blockIdx.x * 4 + (threadIdx.x >> 6);
  int lane = threadIdx.x & 63;
  const float4* xr = reinterpret_cast<const float4*>(x + (size_t)row * D_);
  float4 v0 = xr[lane], v1 = xr[lane + 64];
  float s = v0.x + v0.y + v0.z + v0.w + v1.x + v1.y + v1.z + v1.w;
  float q = v0.x*v0.x + v0.y*v0.y + v0.z*v0.z + v0.w*v0.w
          + v1.x*v1.x + v1.y*v1.y + v1.z*v1.z + v1.w*v1.w;
  #pragma unroll
  for (int off = 1; off < 64; off <<= 1) {
    s += __shfl_xor(s, off);
    q += __shfl_xor(q, off);
  }
  float mean = s * (1.0f / D_);
  float var  = q * (1.0f / D_) - mean * mean;
  float rs   = rsqrtf(var + EPS_);
  const float4* g4 = reinterpret_cast<const float4*>(g);
  const float4* b4 = reinterpret_cast<const float4*>(b);
  float4 gv0 = g4[lane], gv1 = g4[lane + 64];
  float4 bv0 = b4[lane], bv1 = b4[lane + 64];
  ushort4 p0, p1;
  p0.x = f2bf((v0.x - mean) * rs * gv0.x + bv0.x);
  p0.y = f2bf((v0.y - mean) * rs * gv0.y + bv0.y);
  p0.z = f2bf((v0.z - mean) * rs * gv0.z + bv0.z);
  p0.w = f2bf((v0.w - mean) * rs * gv0.w + bv0.w);
  p1.x = f2bf((v1.x - mean) * rs * gv1.x + bv1.x);
  p1.y = f2bf((v1.y - mean) * rs * gv1.y + bv1.y);
  p1.z = f2bf((v1.z - mean) * rs * gv1.z + bv1.z);
  p1.w = f2bf((v1.w - mean) * rs * gv1.w + bv1.w);
  unsigned short* orow = out + (size_t)row * D_;
  *reinterpret_cast<ushort4*>(orow + lane * 4)       = p0;
  *reinterpret_cast<ushort4*>(orow + 256 + lane * 4) = p1;
}

// ---------------------------------------------------------------- transpose+cast fp32 [R][C] -> bf16 [C][R]
__global__ __launch_bounds__(256) void transpose_cast(
    const float* __restrict__ src, unsigned short* __restrict__ dst,
    int C, int R, long sstride, long dstride)
{
  src += (size_t)blockIdx.z * sstride;
  dst += (size_t)blockIdx.z * dstride;
  __shared__ float t[32][33];
  int r0 = blockIdx.x * 32, c0 = blockIdx.y * 32;
  int tx = threadIdx.x & 31, ty = threadIdx.x >> 5;
  #pragma unroll
  for (int i = 0; i < 4; i++)
    t[ty + i*8][tx] = src[(size_t)(r0 + ty + i*8) * C + c0 + tx];
  __syncthreads();
  #pragma unroll
  for (int i = 0; i < 4; i++)
    dst[(size_t)(c0 + ty + i*8) * R + r0 + tx] = f2bf(t[tx][ty + i*8]);
}

// WqkvT[l][mat*512 + h*64 + e][d] = W{q,k,v}[l][h][d][e]
__global__ __launch_bounds__(256) void qkvw_transpose(
    const float* __restrict__ Wq, const float* __restrict__ Wk,
    const float* __restrict__ Wv, unsigned short* __restrict__ dst)
{
  int z = blockIdx.z; int l = z / 24; int rem = z % 24; int mat = rem >> 3; int h = rem & 7;
  const float* W = (mat == 0 ? Wq : (mat == 1 ? Wk : Wv)) + ((size_t)(l * 8 + h)) * D_ * HD_;
  unsigned short* d = dst + ((size_t)l * 1536 + mat * 512 + h * 64) * D_;
  __shared__ float t[32][33];
  int d0 = blockIdx.x * 32, e0 = blockIdx.y * 32;
  int tx = threadIdx.x & 31, ty = threadIdx.x >> 5;
  #pragma unroll
  for (int i = 0; i < 4; i++)
    t[ty + i*8][tx] = W[(size_t)(d0 + ty + i*8) * HD_ + e0 + tx];
  __syncthreads();
  #pragma unroll
  for (int i = 0; i < 4; i++)
    d[(size_t)(e0 + ty + i*8) * D_ + d0 + tx] = f2bf(t[tx][ty + i*8]);
}

// ---------------------------------------------------------------- 256x256 bf16 MFMA GEMM (2-phase dbuf)
// 512 threads, 8 waves (2M x 4N), BK=64, double-buffered LDS (128 KB),
// counted vmcnt(8), XOR chunk swizzle (pre-swizzled global source + swizzled
// ds_read). Optional fused per-panel online-softmax partials (ms != nullptr).
__global__ __launch_bounds__(512, 2) void gemm_big(
    const unsigned short* __restrict__ A,
    const unsigned short* __restrict__ Bt,
    int K,
    const float* __restrict__ bias,
    float* __restrict__ outF,
    unsigned short* __restrict__ outH,
    int ldc, int relu,
    float2* __restrict__ ms, int npan)
{
  __shared__ __align__(16) unsigned short As[2][16384];   // [buf][256 rows x 64]
  __shared__ __align__(16) unsigned short Bs[2][16384];
  const int tid = threadIdx.x;
  const int lane = tid & 63;
  const int lr = lane & 15, g = lane >> 4;
  const int wv = tid >> 6, wm = wv >> 2, wn = wv & 3;

  const int gx = gridDim.x;
  int id = blockIdx.y * gx + blockIdx.x;
  const int nwg = gx * gridDim.y;
  if ((nwg & 7) == 0) { const int q = nwg >> 3; id = (id & 7) * q + (id >> 3); }
  const int bm = (id % gx) * 256, bn = (id / gx) * 256, bnp = id / gx;

  const int srow = tid >> 3;                        // 0..63
  const int schk = (tid & 7) ^ (srow & 7);          // pre-swizzled source chunk
  const unsigned short* Ab = A  + (size_t)(bm + srow) * K + schk * 8;
  const unsigned short* Bb = Bt + (size_t)(bn + srow) * K + schk * 8;

#define STAGEB(t, bf)                                                            \
  { const int kof_ = (t) * 64;                                                   \
    _Pragma("unroll")                                                            \
    for (int i_ = 0; i_ < 4; ++i_) {                                             \
      gl_lds16(Ab + (size_t)(i_ * 64) * K + kof_, &As[bf][i_ * 4096 + tid * 8]); \
      gl_lds16(Bb + (size_t)(i_ * 64) * K + kof_, &Bs[bf][i_ * 4096 + tid * 8]); \
    } }

  f32x4 acc[8][4];
  #pragma unroll
  for (int m = 0; m < 8; m++)
    #pragma unroll
    for (int n = 0; n < 4; n++)
      acc[m][n] = (f32x4){0.f, 0.f, 0.f, 0.f};

  const int nt = K >> 6;
  STAGEB(0, 0);

  for (int t = 0; t < nt; ++t) {
    __builtin_amdgcn_sched_barrier(0);
    if (t + 1 < nt) { STAGEB(t + 1, (t + 1) & 1); WAITVM(8); }
    else            { WAITVM(0); }
    __builtin_amdgcn_sched_barrier(0);
    __builtin_amdgcn_s_barrier();            // tile t landed for all waves
    __builtin_amdgcn_sched_barrier(0);

    const unsigned short* Ac = As[t & 1];
    const unsigned short* Bc = Bs[t & 1];
    #pragma unroll
    for (int kk = 0; kk < 2; ++kk) {
      const int sl = ((kk * 4 + g) ^ (lr & 7)) << 3;
      bf16x8 af[8], bfr[4];
      #pragma unroll
      for (int m = 0; m < 8; m++)
        af[m] = *reinterpret_cast<const bf16x8*>(&Ac[(wm*128 + m*16 + lr) * 64 + sl]);
      #pragma unroll
      for (int n = 0; n < 4; n++)
        bfr[n] = *reinterpret_cast<const bf16x8*>(&Bc[(wn*64 + n*16 + lr) * 64 + sl]);
      #pragma unroll
      for (int m = 0; m < 8; m++)
        #pragma unroll
        for (int n = 0; n < 4; n++)
          acc[m][n] = __builtin_amdgcn_mfma_f32_16x16x32_bf16(af[m], bfr[n], acc[m][n], 0, 0, 0);
    }
    __builtin_amdgcn_sched_barrier(0);
    __builtin_amdgcn_s_barrier();            // all waves done reading buf[t&1]
  }
#undef STAGEB

  // ---- epilogue
  const int cr = g * 4;
  float2* msL = reinterpret_cast<float2*>(&As[0][0]);   // 256 rows x 4 wn
  #pragma unroll
  for (int m = 0; m < 8; m++) {
    float vals[4][4];
    float vmax[4] = {NEGBIG, NEGBIG, NEGBIG, NEGBIG};
    #pragma unroll
    for (int n = 0; n < 4; n++) {
      const int col = bn + wn*64 + n*16 + lr;
      #pragma unroll
      for (int r = 0; r < 4; r++) {
        float v = acc[m][n][r];
        if (bias) v += bias[col];
        if (relu) v = fmaxf(v, 0.f);
        vals[n][r] = v;
        vmax[r] = fmaxf(vmax[r], v);
      }
    }
    const int row = bm + wm*128 + m*16 + cr;
    #pragma unroll
    for (int n = 0; n < 4; n++) {
      const int col = bn + wn*64 + n*16 + lr;
      #pragma unroll
      for (int r = 0; r < 4; r++) {
        if (outF) outF[(size_t)(row + r) * ldc + col] = vals[n][r];
        else      outH[(size_t)(row + r) * ldc + col] = f2bf(vals[n][r]);
      }
    }
    if (ms) {
      #pragma unroll
      for (int r = 0; r < 4; r++) {
        #pragma unroll
        for (int off = 1; off < 16; off <<= 1)
          vmax[r] = fmaxf(vmax[r], __shfl_xor(vmax[r], off));
      }
      float vsum[4] = {0.f, 0.f, 0.f, 0.f};
      #pragma unroll
      for (int n = 0; n < 4; n++)
        #pragma unroll
        for (int r = 0; r < 4; r++)
          vsum[r] += __expf(vals[n][r] - vmax[r]);
      #pragma unroll
      for (int r = 0; r < 4; r++) {
        #pragma unroll
        for (int off = 1; off < 16; off <<= 1)
          vsum[r] += __shfl_xor(vsum[r], off);
      }
      if (lr == 0) {
        #pragma unroll
        for (int r = 0; r < 4; r++)
          msL[(wm*128 + m*16 + g*4 + r) * 4 + wn] = make_float2(vmax[r], vsum[r]);
      }
    }
  }
  if (ms) {
    __syncthreads();
    if (tid < 256) {
      float M = NEGBIG, S = 0.f;
      #pragma unroll
      for (int w = 0; w < 4; w++) {
        float2 e = msL[tid * 4 + w];
        float Mn = fmaxf(M, e.x);
        S = S * __expf(M - Mn) + e.y * __expf(e.x - Mn);
        M = Mn;
      }
      ms[(size_t)(bm + tid) * npan + bnp] = make_float2(M, S);
    }
  }
}

// ---------------------------------------------------------------- pipelined bf16 MFMA GEMM (128xBN, BK=32, depth-3)
template<int BN_T, int WM, int WN>
__global__ __launch_bounds__(256) void gemm_pipe(
    const unsigned short* __restrict__ A,
    const unsigned short* __restrict__ Bt,
    int K,
    const float* __restrict__ bias,
    const float* __restrict__ resid,
    float* __restrict__ outF,
    unsigned short* __restrict__ outH,
    int ldc, int relu)
{
  constexpr int BKp = 32;
  constexpr int ALOADS = 2;
  constexpr int BLOADS = BN_T / 64;
  constexpr int LOADS  = ALOADS + BLOADS;
  constexpr int MR = 128 / (16 * WM);
  constexpr int NR = BN_T / (16 * WN);
  __shared__ __align__(16) unsigned short As[4][128 * BKp];
  __shared__ __align__(16) unsigned short Bs[4][BN_T * BKp];

  const int tid = threadIdx.x;
  const int lane = tid & 63, wv = tid >> 6;
  const int lr = lane & 15, g = lane >> 4;

  const int gx = gridDim.x;
  int id = blockIdx.y * gx + blockIdx.x;
  const int nwg = gx * gridDim.y;
  if ((nwg & 7) == 0) {
    const int q = nwg >> 3;
    id = (id & 7) * q + (id >> 3);
  }
  const int bm = (id % gx) * 128, bn = (id / gx) * BN_T;

  const int m0w = (wv / WN) * (128 / WM);
  const int n0w = (wv % WN) * (BN_T / WN);

  const int schk = (lane & 3) ^ ((lane >> 3) & 3);
  const unsigned short* Ab = A  + (size_t)(bm + wv*32 + (lane >> 2)) * K + schk * 8;
  const unsigned short* Bb = Bt + (size_t)(bn + wv*(BN_T/4) + (lane >> 2)) * K + schk * 8;

#define STAGEP(s)                                                               \
  { const int kof_ = (s) * BKp; unsigned short* Ad_ = As[(s) & 3] + wv*1024;    \
    unsigned short* Bd_ = Bs[(s) & 3] + wv*(BLOADS*512);                        \
    _Pragma("unroll")                                                           \
    for (int i_ = 0; i_ < ALOADS; ++i_)                                         \
      gl_lds16(Ab + (size_t)(i_*16)*K + kof_, Ad_ + i_*512);                    \
    _Pragma("unroll")                                                           \
    for (int i_ = 0; i_ < BLOADS; ++i_)                                         \
      gl_lds16(Bb + (size_t)(i_*16)*K + kof_, Bd_ + i_*512); }

  f32x4 acc[MR][NR];
  #pragma unroll
  for (int m = 0; m < MR; m++)
    #pragma unroll
    for (int n = 0; n < NR; n++)
      acc[m][n] = (f32x4){0.f, 0.f, 0.f, 0.f};

  const int nt = K >> 5;
  STAGEP(0); STAGEP(1); STAGEP(2);

  const int slotx = (g ^ ((lr >> 1) & 3)) << 3;

  for (int t = 0; t < nt; ++t) {
    const int s = t + 3;
    __builtin_amdgcn_sched_barrier(0);
    if (s < nt) {
      STAGEP(s);
      if constexpr (LOADS == 4) WAITVM(12); else WAITVM(9);
    } else if (s == nt) {
      if constexpr (LOADS == 4) WAITVM(8); else WAITVM(6);
    } else if (s == nt + 1) {
      if constexpr (LOADS == 4) WAITVM(4); else WAITVM(3);
    } else {
      WAITVM(0);
    }
    __builtin_amdgcn_sched_barrier(0);
    __builtin_amdgcn_s_barrier();
    __builtin_amdgcn_sched_barrier(0);

    const unsigned short* Ac = As[t & 3];
    const unsigned short* Bc = Bs[t & 3];
    bf16x8 af[MR], bfr[NR];
    #pragma unroll
    for (int m = 0; m < MR; m++)
      af[m] = *reinterpret_cast<const bf16x8*>(&Ac[(m0w + m*16 + lr) * BKp + slotx]);
    #pragma unroll
    for (int n = 0; n < NR; n++)
      bfr[n] = *reinterpret_cast<const bf16x8*>(&Bc[(n0w + n*16 + lr) * BKp + slotx]);
    #pragma unroll
    for (int m = 0; m < MR; m++)
      #pragma unroll
      for (int n = 0; n < NR; n++)
        acc[m][n] = __builtin_amdgcn_mfma_f32_16x16x32_bf16(af[m], bfr[n], acc[m][n], 0, 0, 0);

    __builtin_amdgcn_sched_barrier(0);
    __builtin_amdgcn_s_barrier();
  }
#undef STAGEP

  const int cr = g * 4;
  const int cc = lr;
  #pragma unroll
  for (int m = 0; m < MR; m++) {
    #pragma unroll
    for (int n = 0; n < NR; n++) {
      int row = bm + m0w + m*16 + cr;
      int col = bn + n0w + n*16 + cc;
      f32x4 a = acc[m][n];
      #pragma unroll
      for (int r = 0; r < 4; r++) {
        float v = a[r];
        if (bias)  v += bias[col];
        if (resid) v += resid[(size_t)(row + r) * ldc + col];
        if (relu)  v = fmaxf(v, 0.f);
        if (outF)  outF[(size_t)(row + r) * ldc + col] = v;
        if (outH)  outH[(size_t)(row + r) * ldc + col] = f2bf(v);
      }
    }
  }
}

// ---------------------------------------------------------------- MFMA flash attention (bf16 in/out)
__global__ __launch_bounds__(256) void attn_mfma(
    const unsigned short* __restrict__ qkv,  // bf16 [B*T][1536]
    unsigned short* __restrict__ o)          // bf16 [B*T][512]
{
  __shared__ __align__(16) unsigned short Ks[64*64];
  __shared__ __align__(16) unsigned short Vt[64*64];
  __shared__ __align__(16) unsigned short Ps[4][16*64];

  const int qb = (int)gridDim.x - 1 - (int)blockIdx.x;
  const int bh = blockIdx.y, bb = bh >> 3, hh = bh & 7;
  const int tid = threadIdx.x, lane = tid & 63, wv = tid >> 6;
  const int lr = lane & 15, g = lane >> 4;

  const unsigned short* qp = qkv + ((size_t)(bb*T_ + qb*64))*1536 + hh*64;
  const unsigned short* kp = qkv + ((size_t)bb*T_)*1536 + 512  + hh*64;
  const unsigned short* vp = qkv + ((size_t)bb*T_)*1536 + 1024 + hh*64;

  bf16x8 qf[2];
  qf[0] = *reinterpret_cast<const bf16x8*>(qp + (size_t)(wv*16 + lr)*1536 + g*8);
  qf[1] = *reinterpret_cast<const bf16x8*>(qp + (size_t)(wv*16 + lr)*1536 + 32 + g*8);

  f32x4 ov[4];
  #pragma unroll
  for (int n = 0; n < 4; n++) ov[n] = (f32x4){0.f, 0.f, 0.f, 0.f};
  float mrow[4] = {NEGBIG, NEGBIG, NEGBIG, NEGBIG};
  float lrow[4] = {0.f, 0.f, 0.f, 0.f};

  for (int s0 = 0; s0 <= qb; ++s0) {
    __syncthreads();
    #pragma unroll
    for (int i = 0; i < 2; i++) {
      int kv = i*32 + wv*8 + (lane >> 3);
      int hb = (lane & 7) ^ (lane >> 3);
      gl_lds16(kp + (size_t)(s0*64 + kv)*1536 + hb*8,
               (void*)(Ks + i*2048 + wv*512));
    }
    #pragma unroll
    for (int it = 0; it < 2; it++) {
      int c0 = wv*8 + it*32;
      union { uint4 v; unsigned short e[8]; } uv;
      uv.v = *reinterpret_cast<const uint4*>(vp + (size_t)(s0*64 + lane)*1536 + c0);
      #pragma unroll
      for (int j = 0; j < 8; j++)
        Vt[(c0 + j)*64 + (((lane >> 3) ^ j) << 3) + (lane & 7)] = uv.e[j];
    }
    __syncthreads();

    f32x4 sf[4];
    #pragma unroll
    for (int n = 0; n < 4; n++) sf[n] = (f32x4){0.f, 0.f, 0.f, 0.f};
    #pragma unroll
    for (int kk = 0; kk < 2; kk++) {
      #pragma unroll
      for (int n = 0; n < 4; n++) {
        const bf16x8 kf = *reinterpret_cast<const bf16x8*>(
            &Ks[(n*16 + lr)*64 + (((kk*4 + g) ^ (lr & 7)) << 3)]);
        sf[n] = __builtin_amdgcn_mfma_f32_16x16x32_bf16(qf[kk], kf, sf[n], 0, 0, 0);
      }
    }

    const int diag = (s0 == qb);
    float sv[4][4];
    #pragma unroll
    for (int n = 0; n < 4; n++)
      #pragma unroll
      for (int r = 0; r < 4; r++) {
        float xv = sf[n][r] * SCALE_;
        if (diag && (n*16 + lr) > (wv*16 + g*4 + r)) xv = NEGBIG;
        sv[n][r] = xv;
      }

    float aa[4];
    #pragma unroll
    for (int r = 0; r < 4; r++) {
      float pm = fmaxf(fmaxf(sv[0][r], sv[1][r]), fmaxf(sv[2][r], sv[3][r]));
      pm = fmaxf(pm, __shfl_xor(pm, 1));
      pm = fmaxf(pm, __shfl_xor(pm, 2));
      pm = fmaxf(pm, __shfl_xor(pm, 4));
      pm = fmaxf(pm, __shfl_xor(pm, 8));
      float mn = fmaxf(mrow[r], pm);
      aa[r] = __expf(mrow[r] - mn);
      mrow[r] = mn;
    }
    float rs[4] = {0.f, 0.f, 0.f, 0.f};
    #pragma unroll
    for (int n = 0; n < 4; n++)
      #pragma unroll
      for (int r = 0; r < 4; r++) {
        float p = __expf(sv[n][r] - mrow[r]);
        rs[r] += p;
        Ps[wv][(g*4 + r)*64 + ((((n << 1) + (lr >> 3)) ^ ((g*4 + r) & 7)) << 3) + (lr & 7)] = f2bf(p);
      }
    #pragma unroll
    for (int r = 0; r < 4; r++) {
      float s = rs[r];
      s += __shfl_xor(s, 1); s += __shfl_xor(s, 2);
      s += __shfl_xor(s, 4); s += __shfl_xor(s, 8);
      lrow[r] = lrow[r]*aa[r] + s;
    }
    #pragma unroll
    for (int n = 0; n < 4; n++)
      #pragma unroll
      for (int r = 0; r < 4; r++)
        ov[n][r] *= aa[r];

    #pragma unroll
    for (int kk = 0; kk < 2; kk++) {
      const bf16x8 pf = *reinterpret_cast<const bf16x8*>(
          &Ps[wv][lr*64 + (((kk*4 + g) ^ (lr & 7)) << 3)]);
      #pragma unroll
      for (int n = 0; n < 4; n++) {
        const bf16x8 vf = *reinterpret_cast<const bf16x8*>(
            &Vt[(n*16 + lr)*64 + (((kk*4 + g) ^ (lr & 7)) << 3)]);
        ov[n] = __builtin_amdgcn_mfma_f32_16x16x32_bf16(pf, vf, ov[n], 0, 0, 0);
      }
    }
  }

  #pragma unroll
  for (int r = 0; r < 4; r++) {
    float inv = 1.0f / lrow[r];
    size_t row = (size_t)(bb*T_ + qb*64 + wv*16 + g*4 + r);
    #pragma unroll
    for (int n = 0; n < 4; n++)
      o[row*D_ + hh*64 + n*16 + lr] = f2bf(ov[n][r] * inv);
  }
}

// ---------------------------------------------------------------- loss: merge per-panel partials
__global__ __launch_bounds__(256) void loss_merge_kernel(
    const float2* __restrict__ ms, const float* __restrict__ logits,
    const int* __restrict__ labels, float* __restrict__ rowloss, int npan)
{
  const int tid = threadIdx.x, lane = tid & 63, wid = tid >> 6;
  const int row = blockIdx.x * 4 + wid;
  float M = NEGBIG, S = 0.f;
  const float2* p = ms + (size_t)row * npan;
  for (int i = lane; i < npan; i += 64) {
    float2 e = p[i];
    float Mn = fmaxf(M, e.x);
    S = S * __expf(M - Mn) + e.y * __expf(e.x - Mn);
    M = Mn;
  }
  #pragma unroll
  for (int off = 1; off < 64; off <<= 1) {
    float Mo = __shfl_xor(M, off), So = __shfl_xor(S, off);
    float Mn = fmaxf(M, Mo);
    S = S * __expf(M - Mn) + So * __expf(Mo - Mn);
    M = Mn;
  }
  if (lane == 0)
    rowloss[row] = logits[(size_t)row * V_ + labels[row]] - M - logf(S);
}

__global__ __launch_bounds__(256) void loss_final_kernel(
    const float* __restrict__ rowloss, float* __restrict__ out)
{
  __shared__ float red[4];
  const int tid = threadIdx.x, lane = tid & 63, wid = tid >> 6;
  float s = 0.f;
  for (int i = tid; i < BT_; i += 256) s += rowloss[i];
  #pragma unroll
  for (int off = 1; off < 64; off <<= 1) s += __shfl_xor(s, off);
  if (lane == 0) red[wid] = s;
  __syncthreads();
  if (tid == 0) out[0] = -(red[0] + red[1] + red[2] + red[3]) * (1.0f / BT_);
}

// ---------------------------------------------------------------- launch
extern "C" void kernel_launch(void* const* d_in, const int* in_sizes, int n_in,
                              void* d_out, int out_size, void* d_ws, size_t ws_size,
                              hipStream_t stream)
{
  (void)in_sizes; (void)n_in; (void)out_size; (void)ws_size;
  const int*   ids    = (const int*)d_in[0];
  const int*   labels = (const int*)d_in[1];
  const float* tok    = (const float*)d_in[2];
  const float* pos    = (const float*)d_in[3];
  const float* Wq     = (const float*)d_in[4];
  const float* Wk     = (const float*)d_in[5];
  const float* Wv     = (const float*)d_in[6];
  const float* Wo     = (const float*)d_in[7];
  const float* bo     = (const float*)d_in[8];
  const float* ln1g   = (const float*)d_in[9];
  const float* ln1b   = (const float*)d_in[10];
  const float* ln2g   = (const float*)d_in[11];
  const float* ln2b   = (const float*)d_in[12];
  const float* W1     = (const float*)d_in[13];
  const float* b1     = (const float*)d_in[14];
  const float* W2     = (const float*)d_in[15];
  const float* b2     = (const float*)d_in[16];
  const float* lnfg   = (const float*)d_in[17];
  const float* lnfb   = (const float*)d_in[18];
  const float* Wp     = (const float*)d_in[19];
  const float* bp     = (const float*)d_in[20];

  float* out = (float*)d_out;
  char* base = (char*)d_ws;
  float*          x       = (float*)(base + 0);                 //  8,388,608
  unsigned short* xn      = (unsigned short*)(base + 8388608);  //  4,194,304
  float*          rowloss = (float*)(base + 12582912);          //     16,384
  unsigned short* WqkvT   = (unsigned short*)(base + 12599296); //  6,291,456
  unsigned short* W1T     = (unsigned short*)(base + 18890752); //  8,388,608
  unsigned short* W2T     = (unsigned short*)(base + 27279360); //  8,388,608
  unsigned short* WoT     = (unsigned short*)(base + 35667968); //  2,097,152
  unsigned short* qkvh    = (unsigned short*)(base + 37765120); // 12,582,912
  unsigned short* ob      = (unsigned short*)(base + 50348032); //  4,194,304
  unsigned short* h1      = (unsigned short*)(base + 54542336); // 16,777,216
  unsigned short* WpT     = (unsigned short*)(base + 37765120); // 32,768,000 (alias: dead at logits time)
  float2*         msbuf   = (float2*)(base + 71319552);         //  4,096,000

  embed_kernel<<<BT_ * D_ / 4 / 256, 256, 0, stream>>>(ids, tok, pos, x);

  qkvw_transpose<<<dim3(16, 2, 96), 256, 0, stream>>>(Wq, Wk, Wv, WqkvT);
  transpose_cast<<<dim3(16, 64, 4), 256, 0, stream>>>(W1, W1T, 2048, 512, 1048576, 1048576);
  transpose_cast<<<dim3(64, 16, 4), 256, 0, stream>>>(W2, W2T, 512, 2048, 1048576, 1048576);
  transpose_cast<<<dim3(16, 16, 4), 256, 0, stream>>>(Wo, WoT, 512, 512, 262144, 262144);

  for (int l = 0; l < NL_; l++) {
    ln_kernel<<<BT_ / 4, 256, 0, stream>>>(x, ln1g + l * D_, ln1b + l * D_, xn);
    gemm_big<<<dim3(16, 6), 512, 0, stream>>>(
        xn, WqkvT + (size_t)l * 1536 * 512, 512, nullptr, nullptr, qkvh, 1536, 0, nullptr, 0);
    attn_mfma<<<dim3(T_ / 64, B_ * H_), 256, 0, stream>>>(qkvh, ob);
    gemm_pipe<64,4,1><<<dim3(32, 8), 256, 0, stream>>>(
        ob, WoT + (size_t)l * 512 * 512, 512, bo + l * D_, x, x, nullptr, D_, 0);
    ln_kernel<<<BT_ / 4, 256, 0, stream>>>(x, ln2g + l * D_, ln2b + l * D_, xn);
    gemm_big<<<dim3(16, 8), 512, 0, stream>>>(
        xn, W1T + (size_t)l * 2048 * 512, 512, b1 + l * 4 * D_, nullptr, h1, 4 * D_, 1, nullptr, 0);
    gemm_pipe<64,4,1><<<dim3(32, 8), 256, 0, stream>>>(
        h1, W2T + (size_t)l * 512 * 2048, 2048, b2 + l * D_, x, x, nullptr, D_, 0);
  }

  transpose_cast<<<dim3(16, 1000, 1), 256, 0, stream>>>(Wp, WpT, 32000, 512, 0, 0);
  ln_kernel<<<BT_ / 4, 256, 0, stream>>>(x, lnfg, lnfb, xn);
  gemm_big<<<dim3(16, 125), 512, 0, stream>>>(
      xn, WpT, 512, bp, out, nullptr, V_, 0, msbuf, 125);

  loss_merge_kernel<<<BT_ / 4, 256, 0, stream>>>(msbuf, out, labels, rowloss, 125);
  loss_final_kernel<<<1, 256, 0, stream>>>(rowloss, out + (size_t)BT_ * V_);
}